// Round 3
// baseline (302.167 us; speedup 1.0000x reference)
//
#include <hip/hip_runtime.h>

#define DEVFN __device__ __forceinline__

typedef __attribute__((ext_vector_type(8))) short short8;
typedef __attribute__((ext_vector_type(4))) float float4v;

DEVFN float bf2f(unsigned short u) {
    union { unsigned int i; float f; } c;
    c.i = ((unsigned int)u) << 16;
    return c.f;
}

DEVFN unsigned short f2bf(float f) {
    union { float f; unsigned int i; } c;
    c.f = f;
    unsigned int u = c.i;
    return (unsigned short)((u + 0x7FFFu + ((u >> 16) & 1u)) >> 16);  // RNE
}

// accumulate 8 bf16 (uint4) into 8 fp32
DEVFN void addu4(float* acc, uint4 u) {
    unsigned int w[4] = {u.x, u.y, u.z, u.w};
#pragma unroll
    for (int k = 0; k < 4; k++) {
        union { unsigned int i; float f; } lo, hi;
        lo.i = w[k] << 16;
        hi.i = w[k] & 0xFFFF0000u;
        acc[2 * k]     += lo.f;
        acc[2 * k + 1] += hi.f;
    }
}

// ---------------- deterministic 2-level bucket partition ----------------

#define CHUNK 4096

__global__ __launch_bounds__(256) void k_count(const int* __restrict__ dst,
                                               int* __restrict__ Cmat, int E) {
    __shared__ int lh[1024];
    int t = threadIdx.x;
    for (int b = t; b < 1024; b += 256) lh[b] = 0;
    __syncthreads();
    int i0 = blockIdx.x * CHUNK;
    int i1 = i0 + CHUNK; if (i1 > E) i1 = E;
    for (int i = i0 + t; i < i1; i += 256) atomicAdd(&lh[dst[i] >> 8], 1);
    __syncthreads();
    int* row = Cmat + (size_t)blockIdx.x * 1024;
    for (int b = t; b < 1024; b += 256) row[b] = lh[b];
}

__global__ __launch_bounds__(256) void k_wscan(const int* __restrict__ Cmat,
                                               int* __restrict__ Omat,
                                               int* __restrict__ btot, int gC) {
    int b = (blockIdx.x * 256 + threadIdx.x) >> 6;
    int lane = threadIdx.x & 63;
    int base = 0;
    for (int c0 = 0; c0 < gC; c0 += 64) {
        int c = c0 + lane;
        int x = (c < gC) ? Cmat[(size_t)c * 1024 + b] : 0;
        int orig = x;
#pragma unroll
        for (int off = 1; off < 64; off <<= 1) {
            int y = __shfl_up(x, off);
            if (lane >= off) x += y;
        }
        if (c < gC) Omat[(size_t)c * 1024 + b] = base + x - orig;
        base += __shfl(x, 63);
    }
    if (lane == 0) btot[b] = base;
}

__global__ __launch_bounds__(1024) void k_bscan(const int* __restrict__ btot,
                                                int* __restrict__ boff) {
    __shared__ int s[1024];
    int t = threadIdx.x;
    int v = btot[t];
    s[t] = v;
    __syncthreads();
    for (int o = 1; o < 1024; o <<= 1) {
        int x = (t >= o) ? s[t - o] : 0;
        __syncthreads();
        s[t] += x;
        __syncthreads();
    }
    boff[t] = s[t] - v;
    if (t == 1023) boff[1024] = s[t];
}

__global__ __launch_bounds__(256) void k_part2(const int* __restrict__ src,
                                               const int* __restrict__ dst,
                                               const int* __restrict__ Omat,
                                               const int* __restrict__ boff,
                                               unsigned int* __restrict__ part, int E) {
    __shared__ int lb[1024];
    __shared__ int lc[1024];
    int t = threadIdx.x;
    const int* orow = Omat + (size_t)blockIdx.x * 1024;
    for (int b = t; b < 1024; b += 256) {
        lb[b] = boff[b] + orow[b];
        lc[b] = 0;
    }
    __syncthreads();
    int i0 = blockIdx.x * CHUNK;
    int i1 = i0 + CHUNK; if (i1 > E) i1 = E;
    for (int i = i0 + t; i < i1; i += 256) {
        int d = dst[i];
        int b = d >> 8;
        int r = atomicAdd(&lc[b], 1);
        part[lb[b] + r] = (unsigned int)src[i] | ((unsigned int)(d & 255) << 24);
    }
}

__global__ __launch_bounds__(256) void k_fill_local(const unsigned int* __restrict__ part,
                                                    const int* __restrict__ boff,
                                                    float* __restrict__ dinv,
                                                    int* __restrict__ roff,
                                                    int* __restrict__ csr, int n) {
    __shared__ int lcnt[256];
    __shared__ int lsc[256];
    __shared__ int lcur[256];
    int b = blockIdx.x, t = threadIdx.x;
    int s0 = boff[b], s1 = boff[b + 1];
    lcnt[t] = 0;
    __syncthreads();
    for (int i = s0 + t; i < s1; i += 256) atomicAdd(&lcnt[part[i] >> 24], 1);
    __syncthreads();
    int v = lcnt[t];
    lsc[t] = v;
    __syncthreads();
    for (int o = 1; o < 256; o <<= 1) {
        int x = (t >= o) ? lsc[t - o] : 0;
        __syncthreads();
        lsc[t] += x;
        __syncthreads();
    }
    int excl = lsc[t] - v;
    int node = (b << 8) + t;
    if (node < n) {
        dinv[node] = rsqrtf((float)(v + 1));  // +1 self-loop
        roff[node] = s0 + excl + v;           // END offset
    }
    lcur[t] = s0 + excl;
    __syncthreads();
    for (int i = s0 + t; i < s1; i += 256) {
        unsigned int p = part[i];
        int pos = atomicAdd(&lcur[p >> 24], 1);
        csr[pos] = (int)(p & 0xFFFFFFu);
    }
}

// ---------------- fused prep: head-weight fusion + B-fragment swizzles + bias ----------------
// Wb0: conv0_w (K=128, nt 0..3).  Wb1: conv1_w (K=64, nt 0..3).
// Wfb0: (lin0 @ out_w top half) bf16 swizzled (K=64, nt 0..2, cols 40 padded to 48).
// Wf1p: (lin1 @ out_w bottom half) PLAIN fp32 [64][40] — consumed by fused agg+head.
// bfv[40] = out_b + lin0_b@out_w_top + lin1_b@out_w_bot.
// Wb layout: [ks][nt][lane][j] bf16, value = W[ks*32 + (lane>>4)*8 + j][nt*16 + (lane&15)]
__global__ __launch_bounds__(256) void k_prep(const float* __restrict__ W0,
                                              const float* __restrict__ W1,
                                              const float* __restrict__ lin0_w, const float* __restrict__ lin0_b,
                                              const float* __restrict__ lin1_w, const float* __restrict__ lin1_b,
                                              const float* __restrict__ out_w, const float* __restrict__ out_b,
                                              unsigned short* __restrict__ Wb0,
                                              unsigned short* __restrict__ Wb1,
                                              unsigned short* __restrict__ Wfb0,
                                              float* __restrict__ Wf1p,
                                              float* __restrict__ bfv) {
    int tid = blockIdx.x * 256 + threadIdx.x;
    if (tid < 1024) {
        int ks = tid >> 8, rem = tid & 255;
        int nt = rem >> 6, lane = rem & 63;
        int quad = lane >> 4, c = lane & 15;
        union { unsigned short h[8]; uint4 u; } p;
#pragma unroll
        for (int j = 0; j < 8; j++)
            p.h[j] = f2bf(W0[(ks * 32 + quad * 8 + j) * 64 + nt * 16 + c]);
        *(uint4*)(Wb0 + (size_t)tid * 8) = p.u;
    } else if (tid < 1536) {
        int t2 = tid - 1024;
        int ks = t2 >> 8, rem = t2 & 255;
        int nt = rem >> 6, lane = rem & 63;
        int quad = lane >> 4, c = lane & 15;
        union { unsigned short h[8]; uint4 u; } p;
#pragma unroll
        for (int j = 0; j < 8; j++)
            p.h[j] = f2bf(W1[(ks * 32 + quad * 8 + j) * 64 + nt * 16 + c]);
        *(uint4*)(Wb1 + (size_t)t2 * 8) = p.u;
    } else if (tid < 1920) {
        int t2 = tid - 1536;          // 0..383
        int ks = t2 / 192;
        int rem = t2 % 192;
        int nt = rem >> 6, lane = rem & 63;
        int quad = lane >> 4, c = lane & 15;
        int col = nt * 16 + c;
        union { unsigned short h[8]; uint4 u; } p;
#pragma unroll
        for (int j = 0; j < 8; j++) {
            unsigned short r = 0;
            if (col < 40) {
                int i = ks * 32 + quad * 8 + j;
                float a = 0.f;
                for (int k = 0; k < 64; k++) a += lin0_w[i * 64 + k] * out_w[k * 40 + col];
                r = f2bf(a);
            }
            p.h[j] = r;
        }
        *(uint4*)(Wfb0 + ((size_t)(ks * 3 + nt) * 64 + lane) * 8) = p.u;
    } else if (tid < 1960) {
        int j = tid - 1920;
        float a = out_b[j];
        for (int k = 0; k < 64; k++) {
            a += lin0_b[k] * out_w[k * 40 + j];
            a += lin1_b[k] * out_w[(64 + k) * 40 + j];
        }
        bfv[j] = a;
    } else if (tid < 4520) {
        int t2 = tid - 1960;          // 0..2559
        int i = t2 / 40, c = t2 % 40;
        float a = 0.f;
        for (int k = 0; k < 64; k++) a += lin1_w[i * 64 + k] * out_w[(64 + k) * 40 + c];
        Wf1p[i * 40 + c] = a;         // plain fp32 [64][40]
    }
}

// ---------------- MFMA transform GEMM (layer 0, fp32 input K=128) ----------------

__global__ __launch_bounds__(256) void k_gemm_128(const float* __restrict__ A,
                                                  const unsigned short* __restrict__ Wb,
                                                  const float* __restrict__ dinv,
                                                  unsigned short* __restrict__ Cb, int n) {
    __shared__ unsigned short aLDS[64 * 144];  // 18 KB
    int t = threadIdx.x;
    int r0 = blockIdx.x * 64;
    for (int idx = t; idx < 2048; idx += 256) {   // 64 rows x 32 float4
        int r = idx >> 5;
        int k = (idx & 31) << 2;
        int gr = r0 + r; if (gr >= n) gr = n - 1;
        float4 u = *(const float4*)(A + (size_t)gr * 128 + k);
        int tile = r >> 4, m = r & 15;
        int ks = k >> 5, quad = (k >> 3) & 3, j0 = k & 7;
        int g = (tile * 4 + ks) * 4 + quad;
        union { unsigned short h[4]; uint2 u2; } pk;
        pk.h[0] = f2bf(u.x); pk.h[1] = f2bf(u.y); pk.h[2] = f2bf(u.z); pk.h[3] = f2bf(u.w);
        *(uint2*)(aLDS + g * 144 + m * 8 + j0) = pk.u2;
    }
    int lane = t & 63;
    int w = t >> 6;
    short8 bfr[4][4];
#pragma unroll
    for (int ks = 0; ks < 4; ks++)
#pragma unroll
        for (int nt = 0; nt < 4; nt++)
            bfr[ks][nt] = *(const short8*)(Wb + ((size_t)(ks * 4 + nt) * 64 + lane) * 8);
    __syncthreads();
    int quad = lane >> 4, m = lane & 15;
    short8 afr[4];
#pragma unroll
    for (int ks = 0; ks < 4; ks++)
        afr[ks] = *(const short8*)(aLDS + ((w * 4 + ks) * 4 + quad) * 144 + m * 8);
    float4v acc[4] = {};
#pragma unroll
    for (int nt = 0; nt < 4; nt++)
#pragma unroll
        for (int ks = 0; ks < 4; ks++)
            acc[nt] = __builtin_amdgcn_mfma_f32_16x16x32_bf16(afr[ks], bfr[ks][nt], acc[nt], 0, 0, 0);
    float dv[4];
#pragma unroll
    for (int reg = 0; reg < 4; reg++) {
        int gr = r0 + w * 16 + quad * 4 + reg;
        dv[reg] = (gr < n) ? dinv[gr] : 0.f;
    }
#pragma unroll
    for (int nt = 0; nt < 4; nt++)
#pragma unroll
        for (int reg = 0; reg < 4; reg++) {
            int gr = r0 + w * 16 + quad * 4 + reg;
            if (gr < n) Cb[(size_t)gr * 64 + nt * 16 + m] = f2bf(dv[reg] * acc[nt][reg]);
        }
}

// ---------------- fused mid kernel: Ab = dinv*(Hb@conv1_w), O = Hb@Wf0 ----------------
// One Hb staging feeds both MFMA weight sets.
__global__ __launch_bounds__(256) void k_mid(const unsigned short* __restrict__ Hb,
                                             const unsigned short* __restrict__ Wb,    // conv1, 2ks x 4nt
                                             const unsigned short* __restrict__ Wfb,   // head0, 2ks x 3nt
                                             const float* __restrict__ dinv,
                                             unsigned short* __restrict__ Ab,
                                             float* __restrict__ O, int n) {
    __shared__ unsigned short aLDS[32 * 144];  // 9 KB
    int t = threadIdx.x;
    int r0 = blockIdx.x * 64;
    for (int idx = t; idx < 512; idx += 256) {
        int r = idx >> 3, j = idx & 7;
        int gr = r0 + r; if (gr >= n) gr = n - 1;
        uint4 u = *(const uint4*)(Hb + (size_t)gr * 64 + j * 8);
        int tile = r >> 4, m = r & 15;
        int ks = j >> 2, quad = j & 3;
        *(uint4*)(aLDS + ((tile * 2 + ks) * 4 + quad) * 144 + m * 8) = u;
    }
    int lane = t & 63;
    int w = t >> 6;
    short8 bG[2][4], bH[2][3];
#pragma unroll
    for (int ks = 0; ks < 2; ks++) {
#pragma unroll
        for (int nt = 0; nt < 4; nt++)
            bG[ks][nt] = *(const short8*)(Wb + ((size_t)(ks * 4 + nt) * 64 + lane) * 8);
#pragma unroll
        for (int nt = 0; nt < 3; nt++)
            bH[ks][nt] = *(const short8*)(Wfb + ((size_t)(ks * 3 + nt) * 64 + lane) * 8);
    }
    __syncthreads();
    int quad = lane >> 4, m = lane & 15;
    short8 afr[2];
#pragma unroll
    for (int ks = 0; ks < 2; ks++)
        afr[ks] = *(const short8*)(aLDS + ((w * 2 + ks) * 4 + quad) * 144 + m * 8);
    float4v accG[4] = {};
    float4v accH[3] = {};
#pragma unroll
    for (int nt = 0; nt < 4; nt++)
#pragma unroll
        for (int ks = 0; ks < 2; ks++)
            accG[nt] = __builtin_amdgcn_mfma_f32_16x16x32_bf16(afr[ks], bG[ks][nt], accG[nt], 0, 0, 0);
#pragma unroll
    for (int nt = 0; nt < 3; nt++)
#pragma unroll
        for (int ks = 0; ks < 2; ks++)
            accH[nt] = __builtin_amdgcn_mfma_f32_16x16x32_bf16(afr[ks], bH[ks][nt], accH[nt], 0, 0, 0);
    float dv[4];
#pragma unroll
    for (int reg = 0; reg < 4; reg++) {
        int gr = r0 + w * 16 + quad * 4 + reg;
        dv[reg] = (gr < n) ? dinv[gr] : 0.f;
    }
#pragma unroll
    for (int nt = 0; nt < 4; nt++)
#pragma unroll
        for (int reg = 0; reg < 4; reg++) {
            int gr = r0 + w * 16 + quad * 4 + reg;
            if (gr < n) Ab[(size_t)gr * 64 + nt * 16 + m] = f2bf(dv[reg] * accG[nt][reg]);
        }
#pragma unroll
    for (int nt = 0; nt < 3; nt++) {
        int col = nt * 16 + m;
        if (col < 40) {
#pragma unroll
            for (int reg = 0; reg < 4; reg++) {
                int gr = r0 + w * 16 + quad * 4 + reg;
                if (gr < n) O[(size_t)gr * 40 + col] = accH[nt][reg];
            }
        }
    }
}

// ---------------- aggregation: 2 nodes/wave, 4 lane-groups x 8 feature-lanes per node ----------------
// Half-wave (32 lanes) = one node. uint4 (16 B) row loads; deg-16 node issues 4 loads/lane.
// T is dinv-folded bf16; output Hb bf16.  H[v] = elu( dv*(T'[v] + sum T'[s]) + bias )
__global__ __launch_bounds__(256) void k_agg(const unsigned short* __restrict__ T,
                                             const int* __restrict__ csr,
                                             const int* __restrict__ roffE,  // END offsets
                                             const float* __restrict__ bias,
                                             unsigned short* __restrict__ Hb, int n) {
    int lane = threadIdx.x & 63;
    int half = lane >> 5;              // node within the wave
    int sub = lane & 31;
    int q = sub >> 3, h = sub & 7;     // 4 groups x 8 feature-lanes
    int hb = half << 5;                // shfl base for this node's csr lanes
    int v = blockIdx.x * 8 + ((threadIdx.x >> 6) << 1) + half;
    if (v >= n) return;
    int start = (v == 0) ? 0 : roffE[v - 1];
    int end = roffE[v];
    float dv = rsqrtf((float)(end - start + 1));
    float acc[8] = {0.f, 0.f, 0.f, 0.f, 0.f, 0.f, 0.f, 0.f};
    if (q == 0) {  // self-loop row
        uint4 u = *(const uint4*)(T + (size_t)v * 64 + h * 8);
        addu4(acc, u);
    }
    for (int base = start; base < end; base += 32) {
        int m = end - base; if (m > 32) m = 32;
        int e = (sub < m) ? csr[base + sub] : 0;
        int j = 0;
        for (; j + 16 <= m; j += 16) {
            int s0 = __shfl(e, hb + j + q);
            int s1 = __shfl(e, hb + j + 4 + q);
            int s2 = __shfl(e, hb + j + 8 + q);
            int s3 = __shfl(e, hb + j + 12 + q);
            uint4 u0 = *(const uint4*)(T + (size_t)s0 * 64 + h * 8);
            uint4 u1 = *(const uint4*)(T + (size_t)s1 * 64 + h * 8);
            uint4 u2 = *(const uint4*)(T + (size_t)s2 * 64 + h * 8);
            uint4 u3 = *(const uint4*)(T + (size_t)s3 * 64 + h * 8);
            addu4(acc, u0); addu4(acc, u1); addu4(acc, u2); addu4(acc, u3);
        }
        if (j + 8 <= m) {
            int s0 = __shfl(e, hb + j + q);
            int s1 = __shfl(e, hb + j + 4 + q);
            uint4 u0 = *(const uint4*)(T + (size_t)s0 * 64 + h * 8);
            uint4 u1 = *(const uint4*)(T + (size_t)s1 * 64 + h * 8);
            addu4(acc, u0); addu4(acc, u1);
            j += 8;
        }
        if (j + 4 <= m) {
            int s = __shfl(e, hb + j + q);
            uint4 u = *(const uint4*)(T + (size_t)s * 64 + h * 8);
            addu4(acc, u);
            j += 4;
        }
        if (j < m) {
            int jj = j + q;
            int s = __shfl(e, hb + (jj & 31));
            if (jj < m) {
                uint4 u = *(const uint4*)(T + (size_t)s * 64 + h * 8);
                addu4(acc, u);
            }
        }
    }
#pragma unroll
    for (int i = 0; i < 8; i++) {
        acc[i] += __shfl_xor(acc[i], 8);
        acc[i] += __shfl_xor(acc[i], 16);
    }
    if (q == 0) {
        float4 b0 = *(const float4*)(bias + h * 8);
        float4 b1 = *(const float4*)(bias + h * 8 + 4);
        float bb[8] = {b0.x, b0.y, b0.z, b0.w, b1.x, b1.y, b1.z, b1.w};
        union { unsigned short hh[8]; uint4 u; } p;
#pragma unroll
        for (int i = 0; i < 8; i++) {
            float r = dv * acc[i] + bb[i];
            r = (r > 0.f) ? r : (__expf(r) - 1.f);
            p.hh[i] = f2bf(r);
        }
        *(uint4*)(Hb + (size_t)v * 64 + h * 8) = p.u;
    }
}

// ---------------- fused aggregation + final head (layer-1 pass) ----------------
// Same gather as k_agg; then instead of storing Hb, computes
//   O[v] += elu(dv*agg + conv1_b) @ Wf1 + bfv   (fp32 H, fp32 weights)
// After the q-reduce ALL 32 lanes hold the full acc slice for their h —
// q-group g computes output cols g*10..g*10+9 against LDS-staged Wf1 (stride 41,
// 2-way banks = free), then h-reduce via shfl_xor 1/2/4.
__global__ __launch_bounds__(256) void k_agg_head(const unsigned short* __restrict__ T,
                                                  const int* __restrict__ csr,
                                                  const int* __restrict__ roffE,
                                                  const float* __restrict__ bias,
                                                  const float* __restrict__ Wf1p,  // [64][40] f32
                                                  const float* __restrict__ bfv,   // [40]
                                                  float* __restrict__ O, int n) {
    __shared__ float Ws[64 * 41];  // 10.25 KB, padded stride
    int t = threadIdx.x;
    for (int idx = t; idx < 2560; idx += 256) {
        int k = idx / 40, c = idx % 40;
        Ws[k * 41 + c] = Wf1p[idx];
    }
    __syncthreads();
    int lane = t & 63;
    int half = lane >> 5;
    int sub = lane & 31;
    int q = sub >> 3, h = sub & 7;
    int hb = half << 5;
    int v = blockIdx.x * 8 + ((t >> 6) << 1) + half;
    if (v >= n) return;
    int start = (v == 0) ? 0 : roffE[v - 1];
    int end = roffE[v];
    float dv = rsqrtf((float)(end - start + 1));
    float acc[8] = {0.f, 0.f, 0.f, 0.f, 0.f, 0.f, 0.f, 0.f};
    if (q == 0) {  // self-loop row
        uint4 u = *(const uint4*)(T + (size_t)v * 64 + h * 8);
        addu4(acc, u);
    }
    for (int base = start; base < end; base += 32) {
        int m = end - base; if (m > 32) m = 32;
        int e = (sub < m) ? csr[base + sub] : 0;
        int j = 0;
        for (; j + 16 <= m; j += 16) {
            int s0 = __shfl(e, hb + j + q);
            int s1 = __shfl(e, hb + j + 4 + q);
            int s2 = __shfl(e, hb + j + 8 + q);
            int s3 = __shfl(e, hb + j + 12 + q);
            uint4 u0 = *(const uint4*)(T + (size_t)s0 * 64 + h * 8);
            uint4 u1 = *(const uint4*)(T + (size_t)s1 * 64 + h * 8);
            uint4 u2 = *(const uint4*)(T + (size_t)s2 * 64 + h * 8);
            uint4 u3 = *(const uint4*)(T + (size_t)s3 * 64 + h * 8);
            addu4(acc, u0); addu4(acc, u1); addu4(acc, u2); addu4(acc, u3);
        }
        if (j + 8 <= m) {
            int s0 = __shfl(e, hb + j + q);
            int s1 = __shfl(e, hb + j + 4 + q);
            uint4 u0 = *(const uint4*)(T + (size_t)s0 * 64 + h * 8);
            uint4 u1 = *(const uint4*)(T + (size_t)s1 * 64 + h * 8);
            addu4(acc, u0); addu4(acc, u1);
            j += 8;
        }
        if (j + 4 <= m) {
            int s = __shfl(e, hb + j + q);
            uint4 u = *(const uint4*)(T + (size_t)s * 64 + h * 8);
            addu4(acc, u);
            j += 4;
        }
        if (j < m) {
            int jj = j + q;
            int s = __shfl(e, hb + (jj & 31));
            if (jj < m) {
                uint4 u = *(const uint4*)(T + (size_t)s * 64 + h * 8);
                addu4(acc, u);
            }
        }
    }
#pragma unroll
    for (int i = 0; i < 8; i++) {
        acc[i] += __shfl_xor(acc[i], 8);
        acc[i] += __shfl_xor(acc[i], 16);
    }
    // all lanes: fp32 H slice for features h*8 .. h*8+7
    float4 b0 = *(const float4*)(bias + h * 8);
    float4 b1 = *(const float4*)(bias + h * 8 + 4);
    float bb[8] = {b0.x, b0.y, b0.z, b0.w, b1.x, b1.y, b1.z, b1.w};
    float r[8];
#pragma unroll
    for (int i = 0; i < 8; i++) {
        float x = dv * acc[i] + bb[i];
        r[i] = (x > 0.f) ? x : (__expf(x) - 1.f);
    }
    // head: q-group computes cols q*10 .. q*10+9
    const float* wrow = Ws + (h * 8) * 41 + q * 10;
    float p[10];
#pragma unroll
    for (int j = 0; j < 10; j++) {
        float s = 0.f;
#pragma unroll
        for (int i = 0; i < 8; i++) s += r[i] * wrow[i * 41 + j];
        p[j] = s;
    }
#pragma unroll
    for (int j = 0; j < 10; j++) {
        p[j] += __shfl_xor(p[j], 1);
        p[j] += __shfl_xor(p[j], 2);
        p[j] += __shfl_xor(p[j], 4);
    }
    int c0 = q * 10;
    size_t ob = (size_t)v * 40 + c0;
    // static-index writes (avoid runtime-indexed register array -> scratch)
#pragma unroll
    for (int j = 0; j < 8; j++)
        if (h == j) O[ob + j] += p[j] + bfv[c0 + j];
    if (h == 0) O[ob + 8] += p[8] + bfv[c0 + 8];
    if (h == 1) O[ob + 9] += p[9] + bfv[c0 + 9];
}

// ---------------- launch ----------------

extern "C" void kernel_launch(void* const* d_in, const int* in_sizes, int n_in,
                              void* d_out, int out_size, void* d_ws, size_t ws_size,
                              hipStream_t stream) {
    const float* x       = (const float*)d_in[0];
    const int*   eidx    = (const int*)d_in[1];
    const float* conv0_w = (const float*)d_in[2];
    const float* conv0_b = (const float*)d_in[3];
    const float* lin0_w  = (const float*)d_in[4];
    const float* lin0_b  = (const float*)d_in[5];
    const float* conv1_w = (const float*)d_in[6];
    const float* conv1_b = (const float*)d_in[7];
    const float* lin1_w  = (const float*)d_in[8];
    const float* lin1_b  = (const float*)d_in[9];
    const float* out_w   = (const float*)d_in[10];
    const float* out_b   = (const float*)d_in[11];

    int n = in_sizes[0] / 128;
    int E = in_sizes[1] / 2;
    const int* src = eidx;
    const int* dst = eidx + E;
    int NB = (n + 255) >> 8;
    int gC = (E + CHUNK - 1) / CHUNK;

    char* wsb = (char*)d_ws;
    auto al = [](size_t v) { return (v + 4095) & ~(size_t)4095; };
    size_t o = 0;
    int*            Cmat  = (int*)(wsb + o);            o = al(o + (size_t)gC * 1024 * 4);
    int*            Omat  = (int*)(wsb + o);            o = al(o + (size_t)gC * 1024 * 4);
    int*            btot  = (int*)(wsb + o);            o = al(o + 1024 * 4);
    int*            boff  = (int*)(wsb + o);            o = al(o + 1025 * 4);
    float*          dinv  = (float*)(wsb + o);          o = al(o + (size_t)n * 4);
    int*            roff  = (int*)(wsb + o);            o = al(o + (size_t)n * 4);
    unsigned int*   part  = (unsigned int*)(wsb + o);   o = al(o + (size_t)E * 4);
    int*            csr   = (int*)(wsb + o);            o = al(o + (size_t)E * 4);
    float*          bfv   = (float*)(wsb + o);          o = al(o + 40 * 4);
    unsigned short* Wb0   = (unsigned short*)(wsb + o); o = al(o + 8192 * 2);
    unsigned short* Wb1   = (unsigned short*)(wsb + o); o = al(o + 4096 * 2);
    unsigned short* Wfb0  = (unsigned short*)(wsb + o); o = al(o + 3072 * 2);
    float*          Wf1p  = (float*)(wsb + o);          o = al(o + 2560 * 4);
    unsigned short* Ab    = (unsigned short*)(wsb + o); o = al(o + (size_t)n * 64 * 2);
    unsigned short* Hb    = (unsigned short*)(wsb + o); o = al(o + (size_t)n * 64 * 2);
    float* O = (float*)d_out;

    int gT = (n + 63) / 64;     // MFMA gemms: 64 rows/block
    int gV = (n + 7) / 8;       // agg: 8 nodes/block (2 per wave)

    // CSR build — fully deterministic offsets, no inter-block atomics, no memset
    k_count<<<gC, 256, 0, stream>>>(dst, Cmat, E);
    k_wscan<<<256, 256, 0, stream>>>(Cmat, Omat, btot, gC);
    k_bscan<<<1, 1024, 0, stream>>>(btot, boff);
    k_part2<<<gC, 256, 0, stream>>>(src, dst, Omat, boff, part, E);
    k_fill_local<<<NB, 256, 0, stream>>>(part, boff, dinv, roff, csr, n);
    k_prep<<<18, 256, 0, stream>>>(conv0_w, conv1_w, lin0_w, lin0_b, lin1_w, lin1_b,
                                   out_w, out_b, Wb0, Wb1, Wfb0, Wf1p, bfv);

    // layer 0
    k_gemm_128<<<gT, 256, 0, stream>>>(x, Wb0, dinv, Ab, n);
    k_agg<<<gV, 256, 0, stream>>>(Ab, csr, roff, conv0_b, Hb, n);
    // fused: Ab = dinv*(Hb@conv1_w), O = Hb@Wf0
    k_mid<<<gT, 256, 0, stream>>>(Hb, Wb1, Wfb0, dinv, Ab, O, n);
    // layer 1: fused aggregation + final head (O += H1 @ Wf1 + bfv)
    k_agg_head<<<gV, 256, 0, stream>>>(Ab, csr, roff, conv1_b, Wf1p, bfv, O, n);
}

// Round 6
// 275.899 us; speedup vs baseline: 1.0952x; 1.0952x over previous
//
#include <hip/hip_runtime.h>

#define DEVFN __device__ __forceinline__

typedef __attribute__((ext_vector_type(8))) short short8;
typedef __attribute__((ext_vector_type(4))) float float4v;

DEVFN float bf2f(unsigned short u) {
    union { unsigned int i; float f; } c;
    c.i = ((unsigned int)u) << 16;
    return c.f;
}

DEVFN unsigned short f2bf(float f) {
    union { float f; unsigned int i; } c;
    c.f = f;
    unsigned int u = c.i;
    return (unsigned short)((u + 0x7FFFu + ((u >> 16) & 1u)) >> 16);  // RNE
}

// accumulate 8 bf16 (uint4) into 8 fp32
DEVFN void addu4(float* acc, uint4 u) {
    unsigned int w[4] = {u.x, u.y, u.z, u.w};
#pragma unroll
    for (int k = 0; k < 4; k++) {
        union { unsigned int i; float f; } lo, hi;
        lo.i = w[k] << 16;
        hi.i = w[k] & 0xFFFF0000u;
        acc[2 * k]     += lo.f;
        acc[2 * k + 1] += hi.f;
    }
}

// ---------------- deterministic 2-level bucket partition ----------------

#define CHUNK 4096

__global__ __launch_bounds__(256) void k_count(const int* __restrict__ dst,
                                               int* __restrict__ Cmat, int E) {
    __shared__ int lh[1024];
    int t = threadIdx.x;
    for (int b = t; b < 1024; b += 256) lh[b] = 0;
    __syncthreads();
    int i0 = blockIdx.x * CHUNK;
    int i1 = i0 + CHUNK; if (i1 > E) i1 = E;
    for (int i = i0 + t; i < i1; i += 256) atomicAdd(&lh[dst[i] >> 8], 1);
    __syncthreads();
    int* row = Cmat + (size_t)blockIdx.x * 1024;
    for (int b = t; b < 1024; b += 256) row[b] = lh[b];
}

__global__ __launch_bounds__(256) void k_wscan(const int* __restrict__ Cmat,
                                               int* __restrict__ Omat,
                                               int* __restrict__ btot, int gC) {
    int b = (blockIdx.x * 256 + threadIdx.x) >> 6;
    int lane = threadIdx.x & 63;
    int base = 0;
    for (int c0 = 0; c0 < gC; c0 += 64) {
        int c = c0 + lane;
        int x = (c < gC) ? Cmat[(size_t)c * 1024 + b] : 0;
        int orig = x;
#pragma unroll
        for (int off = 1; off < 64; off <<= 1) {
            int y = __shfl_up(x, off);
            if (lane >= off) x += y;
        }
        if (c < gC) Omat[(size_t)c * 1024 + b] = base + x - orig;
        base += __shfl(x, 63);
    }
    if (lane == 0) btot[b] = base;
}

__global__ __launch_bounds__(1024) void k_bscan(const int* __restrict__ btot,
                                                int* __restrict__ boff) {
    __shared__ int s[1024];
    int t = threadIdx.x;
    int v = btot[t];
    s[t] = v;
    __syncthreads();
    for (int o = 1; o < 1024; o <<= 1) {
        int x = (t >= o) ? s[t - o] : 0;
        __syncthreads();
        s[t] += x;
        __syncthreads();
    }
    boff[t] = s[t] - v;
    if (t == 1023) boff[1024] = s[t];
}

__global__ __launch_bounds__(256) void k_part2(const int* __restrict__ src,
                                               const int* __restrict__ dst,
                                               const int* __restrict__ Omat,
                                               const int* __restrict__ boff,
                                               unsigned int* __restrict__ part, int E) {
    __shared__ int lb[1024];
    __shared__ int lc[1024];
    int t = threadIdx.x;
    const int* orow = Omat + (size_t)blockIdx.x * 1024;
    for (int b = t; b < 1024; b += 256) {
        lb[b] = boff[b] + orow[b];
        lc[b] = 0;
    }
    __syncthreads();
    int i0 = blockIdx.x * CHUNK;
    int i1 = i0 + CHUNK; if (i1 > E) i1 = E;
    for (int i = i0 + t; i < i1; i += 256) {
        int d = dst[i];
        int b = d >> 8;
        int r = atomicAdd(&lc[b], 1);
        part[lb[b] + r] = (unsigned int)src[i] | ((unsigned int)(d & 255) << 24);
    }
}

__global__ __launch_bounds__(256) void k_fill_local(const unsigned int* __restrict__ part,
                                                    const int* __restrict__ boff,
                                                    float* __restrict__ dinv,
                                                    int* __restrict__ roff,
                                                    int* __restrict__ csr, int n) {
    __shared__ int lcnt[256];
    __shared__ int lsc[256];
    __shared__ int lcur[256];
    int b = blockIdx.x, t = threadIdx.x;
    int s0 = boff[b], s1 = boff[b + 1];
    lcnt[t] = 0;
    __syncthreads();
    for (int i = s0 + t; i < s1; i += 256) atomicAdd(&lcnt[part[i] >> 24], 1);
    __syncthreads();
    int v = lcnt[t];
    lsc[t] = v;
    __syncthreads();
    for (int o = 1; o < 256; o <<= 1) {
        int x = (t >= o) ? lsc[t - o] : 0;
        __syncthreads();
        lsc[t] += x;
        __syncthreads();
    }
    int excl = lsc[t] - v;
    int node = (b << 8) + t;
    if (node < n) {
        dinv[node] = rsqrtf((float)(v + 1));  // +1 self-loop
        roff[node] = s0 + excl + v;           // END offset
    }
    lcur[t] = s0 + excl;
    __syncthreads();
    for (int i = s0 + t; i < s1; i += 256) {
        unsigned int p = part[i];
        int pos = atomicAdd(&lcur[p >> 24], 1);
        csr[pos] = (int)(p & 0xFFFFFFu);
    }
}

// ---------------- fused prep: head-weight fusion + all B-fragment swizzles + bias ----------------
// Wb0: conv0_w (K=128, nt 0..3).  Wb1: conv1_w (K=64, nt 0..3).
// Wfb0/Wfb1: (lin @ out_w half) computed on the fly (K=64, nt 0..2, cols 40 padded to 48).
// bfv[40] = out_b + lin0_b@out_w_top + lin1_b@out_w_bot.
// Also zeroes the gather sentinel row Ab[n] (row n, 128 B).
// Wb layout: [ks][nt][lane][j] bf16, value = W[ks*32 + (lane>>4)*8 + j][nt*16 + (lane&15)]
__global__ __launch_bounds__(256) void k_prep(const float* __restrict__ W0,
                                              const float* __restrict__ W1,
                                              const float* __restrict__ lin0_w, const float* __restrict__ lin0_b,
                                              const float* __restrict__ lin1_w, const float* __restrict__ lin1_b,
                                              const float* __restrict__ out_w, const float* __restrict__ out_b,
                                              unsigned short* __restrict__ Wb0,
                                              unsigned short* __restrict__ Wb1,
                                              unsigned short* __restrict__ Wfb0,
                                              unsigned short* __restrict__ Wfb1,
                                              float* __restrict__ bfv,
                                              unsigned short* __restrict__ Ab, int n) {
    int tid = blockIdx.x * 256 + threadIdx.x;
    if (tid < 1024) {
        int ks = tid >> 8, rem = tid & 255;
        int nt = rem >> 6, lane = rem & 63;
        int quad = lane >> 4, c = lane & 15;
        union { unsigned short h[8]; uint4 u; } p;
#pragma unroll
        for (int j = 0; j < 8; j++)
            p.h[j] = f2bf(W0[(ks * 32 + quad * 8 + j) * 64 + nt * 16 + c]);
        *(uint4*)(Wb0 + (size_t)tid * 8) = p.u;
    } else if (tid < 1536) {
        int t2 = tid - 1024;
        int ks = t2 >> 8, rem = t2 & 255;
        int nt = rem >> 6, lane = rem & 63;
        int quad = lane >> 4, c = lane & 15;
        union { unsigned short h[8]; uint4 u; } p;
#pragma unroll
        for (int j = 0; j < 8; j++)
            p.h[j] = f2bf(W1[(ks * 32 + quad * 8 + j) * 64 + nt * 16 + c]);
        *(uint4*)(Wb1 + (size_t)t2 * 8) = p.u;
    } else if (tid < 1920) {
        int t2 = tid - 1536;          // 0..383
        int ks = t2 / 192;
        int rem = t2 % 192;
        int nt = rem >> 6, lane = rem & 63;
        int quad = lane >> 4, c = lane & 15;
        int col = nt * 16 + c;
        union { unsigned short h[8]; uint4 u; } p;
#pragma unroll
        for (int j = 0; j < 8; j++) {
            unsigned short r = 0;
            if (col < 40) {
                int i = ks * 32 + quad * 8 + j;
                float a = 0.f;
                for (int k = 0; k < 64; k++) a += lin0_w[i * 64 + k] * out_w[k * 40 + col];
                r = f2bf(a);
            }
            p.h[j] = r;
        }
        *(uint4*)(Wfb0 + ((size_t)(ks * 3 + nt) * 64 + lane) * 8) = p.u;
    } else if (tid < 2304) {
        int t2 = tid - 1920;
        int ks = t2 / 192;
        int rem = t2 % 192;
        int nt = rem >> 6, lane = rem & 63;
        int quad = lane >> 4, c = lane & 15;
        int col = nt * 16 + c;
        union { unsigned short h[8]; uint4 u; } p;
#pragma unroll
        for (int j = 0; j < 8; j++) {
            unsigned short r = 0;
            if (col < 40) {
                int i = ks * 32 + quad * 8 + j;
                float a = 0.f;
                for (int k = 0; k < 64; k++) a += lin1_w[i * 64 + k] * out_w[(64 + k) * 40 + col];
                r = f2bf(a);
            }
            p.h[j] = r;
        }
        *(uint4*)(Wfb1 + ((size_t)(ks * 3 + nt) * 64 + lane) * 8) = p.u;
    } else if (tid < 2344) {
        int j = tid - 2304;
        float a = out_b[j];
        for (int k = 0; k < 64; k++) {
            a += lin0_b[k] * out_w[k * 40 + j];
            a += lin1_b[k] * out_w[(64 + k) * 40 + j];
        }
        bfv[j] = a;
    } else if (tid < 2352) {
        // zero sentinel row Ab[n] (8 threads x 16 B = 128 B)
        uint4 z = {0u, 0u, 0u, 0u};
        *(uint4*)(Ab + (size_t)n * 64 + (tid - 2344) * 8) = z;
    }
}

// ---------------- MFMA transform GEMM (layer 0, fp32 input K=128) ----------------

__global__ __launch_bounds__(256) void k_gemm_128(const float* __restrict__ A,
                                                  const unsigned short* __restrict__ Wb,
                                                  const float* __restrict__ dinv,
                                                  unsigned short* __restrict__ Cb, int n) {
    __shared__ unsigned short aLDS[64 * 144];  // 18 KB
    int t = threadIdx.x;
    int r0 = blockIdx.x * 64;
    for (int idx = t; idx < 2048; idx += 256) {   // 64 rows x 32 float4
        int r = idx >> 5;
        int k = (idx & 31) << 2;
        int gr = r0 + r; if (gr >= n) gr = n - 1;
        float4 u = *(const float4*)(A + (size_t)gr * 128 + k);
        int tile = r >> 4, m = r & 15;
        int ks = k >> 5, quad = (k >> 3) & 3, j0 = k & 7;
        int g = (tile * 4 + ks) * 4 + quad;
        union { unsigned short h[4]; uint2 u2; } pk;
        pk.h[0] = f2bf(u.x); pk.h[1] = f2bf(u.y); pk.h[2] = f2bf(u.z); pk.h[3] = f2bf(u.w);
        *(uint2*)(aLDS + g * 144 + m * 8 + j0) = pk.u2;
    }
    int lane = t & 63;
    int w = t >> 6;
    short8 bfr[4][4];
#pragma unroll
    for (int ks = 0; ks < 4; ks++)
#pragma unroll
        for (int nt = 0; nt < 4; nt++)
            bfr[ks][nt] = *(const short8*)(Wb + ((size_t)(ks * 4 + nt) * 64 + lane) * 8);
    __syncthreads();
    int quad = lane >> 4, m = lane & 15;
    short8 afr[4];
#pragma unroll
    for (int ks = 0; ks < 4; ks++)
        afr[ks] = *(const short8*)(aLDS + ((w * 4 + ks) * 4 + quad) * 144 + m * 8);
    float4v acc[4] = {};
#pragma unroll
    for (int nt = 0; nt < 4; nt++)
#pragma unroll
        for (int ks = 0; ks < 4; ks++)
            acc[nt] = __builtin_amdgcn_mfma_f32_16x16x32_bf16(afr[ks], bfr[ks][nt], acc[nt], 0, 0, 0);
    float dv[4];
#pragma unroll
    for (int reg = 0; reg < 4; reg++) {
        int gr = r0 + w * 16 + quad * 4 + reg;
        dv[reg] = (gr < n) ? dinv[gr] : 0.f;
    }
#pragma unroll
    for (int nt = 0; nt < 4; nt++)
#pragma unroll
        for (int reg = 0; reg < 4; reg++) {
            int gr = r0 + w * 16 + quad * 4 + reg;
            if (gr < n) Cb[(size_t)gr * 64 + nt * 16 + m] = f2bf(dv[reg] * acc[nt][reg]);
        }
}

// ---------------- fused mid kernel: Ab = dinv*(Hb@conv1_w), O = Hb@Wf0 ----------------
__global__ __launch_bounds__(256) void k_mid(const unsigned short* __restrict__ Hb,
                                             const unsigned short* __restrict__ Wb,    // conv1, 2ks x 4nt
                                             const unsigned short* __restrict__ Wfb,   // head0, 2ks x 3nt
                                             const float* __restrict__ dinv,
                                             unsigned short* __restrict__ Ab,
                                             float* __restrict__ O, int n) {
    __shared__ unsigned short aLDS[32 * 144];  // 9 KB
    int t = threadIdx.x;
    int r0 = blockIdx.x * 64;
    for (int idx = t; idx < 512; idx += 256) {
        int r = idx >> 3, j = idx & 7;
        int gr = r0 + r; if (gr >= n) gr = n - 1;
        uint4 u = *(const uint4*)(Hb + (size_t)gr * 64 + j * 8);
        int tile = r >> 4, m = r & 15;
        int ks = j >> 2, quad = j & 3;
        *(uint4*)(aLDS + ((tile * 2 + ks) * 4 + quad) * 144 + m * 8) = u;
    }
    int lane = t & 63;
    int w = t >> 6;
    short8 bG[2][4], bH[2][3];
#pragma unroll
    for (int ks = 0; ks < 2; ks++) {
#pragma unroll
        for (int nt = 0; nt < 4; nt++)
            bG[ks][nt] = *(const short8*)(Wb + ((size_t)(ks * 4 + nt) * 64 + lane) * 8);
#pragma unroll
        for (int nt = 0; nt < 3; nt++)
            bH[ks][nt] = *(const short8*)(Wfb + ((size_t)(ks * 3 + nt) * 64 + lane) * 8);
    }
    __syncthreads();
    int quad = lane >> 4, m = lane & 15;
    short8 afr[2];
#pragma unroll
    for (int ks = 0; ks < 2; ks++)
        afr[ks] = *(const short8*)(aLDS + ((w * 2 + ks) * 4 + quad) * 144 + m * 8);
    float4v accG[4] = {};
    float4v accH[3] = {};
#pragma unroll
    for (int nt = 0; nt < 4; nt++)
#pragma unroll
        for (int ks = 0; ks < 2; ks++)
            accG[nt] = __builtin_amdgcn_mfma_f32_16x16x32_bf16(afr[ks], bG[ks][nt], accG[nt], 0, 0, 0);
#pragma unroll
    for (int nt = 0; nt < 3; nt++)
#pragma unroll
        for (int ks = 0; ks < 2; ks++)
            accH[nt] = __builtin_amdgcn_mfma_f32_16x16x32_bf16(afr[ks], bH[ks][nt], accH[nt], 0, 0, 0);
    float dv[4];
#pragma unroll
    for (int reg = 0; reg < 4; reg++) {
        int gr = r0 + w * 16 + quad * 4 + reg;
        dv[reg] = (gr < n) ? dinv[gr] : 0.f;
    }
#pragma unroll
    for (int nt = 0; nt < 4; nt++)
#pragma unroll
        for (int reg = 0; reg < 4; reg++) {
            int gr = r0 + w * 16 + quad * 4 + reg;
            if (gr < n) Ab[(size_t)gr * 64 + nt * 16 + m] = f2bf(dv[reg] * accG[nt][reg]);
        }
#pragma unroll
    for (int nt = 0; nt < 3; nt++) {
        int col = nt * 16 + m;
        if (col < 40) {
#pragma unroll
            for (int reg = 0; reg < 4; reg++) {
                int gr = r0 + w * 16 + quad * 4 + reg;
                if (gr < n) O[(size_t)gr * 40 + col] = accH[nt][reg];
            }
        }
    }
}

// ---------------- final head: O += Hb @ Wf1 + bf ----------------
__global__ __launch_bounds__(256) void k_head(const unsigned short* __restrict__ Hb,
                                              const unsigned short* __restrict__ Wfb,
                                              const float* __restrict__ bfv,
                                              float* __restrict__ O, int n) {
    __shared__ unsigned short aLDS[32 * 144];  // 9 KB
    int t = threadIdx.x;
    int r0 = blockIdx.x * 64;
    for (int idx = t; idx < 512; idx += 256) {
        int r = idx >> 3, j = idx & 7;
        int gr = r0 + r; if (gr >= n) gr = n - 1;
        uint4 u = *(const uint4*)(Hb + (size_t)gr * 64 + j * 8);
        int tile = r >> 4, m = r & 15;
        int ks = j >> 2, quad = j & 3;
        *(uint4*)(aLDS + ((tile * 2 + ks) * 4 + quad) * 144 + m * 8) = u;
    }
    int lane = t & 63;
    int w = t >> 6;
    short8 bfr[2][3];
#pragma unroll
    for (int ks = 0; ks < 2; ks++)
#pragma unroll
        for (int nt = 0; nt < 3; nt++)
            bfr[ks][nt] = *(const short8*)(Wfb + ((size_t)(ks * 3 + nt) * 64 + lane) * 8);
    __syncthreads();
    int quad = lane >> 4, m = lane & 15;
    short8 afr[2];
#pragma unroll
    for (int ks = 0; ks < 2; ks++)
        afr[ks] = *(const short8*)(aLDS + ((w * 2 + ks) * 4 + quad) * 144 + m * 8);
    float4v acc[3] = {};
#pragma unroll
    for (int nt = 0; nt < 3; nt++)
#pragma unroll
        for (int ks = 0; ks < 2; ks++)
            acc[nt] = __builtin_amdgcn_mfma_f32_16x16x32_bf16(afr[ks], bfr[ks][nt], acc[nt], 0, 0, 0);
#pragma unroll
    for (int nt = 0; nt < 3; nt++) {
        int col = nt * 16 + m;
        if (col < 40) {
            float bb = bfv[col];
#pragma unroll
            for (int reg = 0; reg < 4; reg++) {
                int gr = r0 + w * 16 + quad * 4 + reg;
                if (gr < n) {
                    size_t p = (size_t)gr * 40 + col;
                    O[p] = O[p] + acc[nt][reg] + bb;
                }
            }
        }
    }
}

// ---------------- generic per-node aggregation loop (rare deg>32 path) ----------------
DEVFN void agg_loop(const unsigned short* __restrict__ T, const int* __restrict__ csr,
                    int start, int end, int hb, int sub, int q, int h, float* acc) {
    for (int base = start; base < end; base += 32) {
        int m = end - base; if (m > 32) m = 32;
        int e = (sub < m) ? csr[base + sub] : 0;
        int j = 0;
        for (; j + 16 <= m; j += 16) {
            int s0 = __shfl(e, hb + j + q);
            int s1 = __shfl(e, hb + j + 4 + q);
            int s2 = __shfl(e, hb + j + 8 + q);
            int s3 = __shfl(e, hb + j + 12 + q);
            uint4 u0 = *(const uint4*)(T + (size_t)s0 * 64 + h * 8);
            uint4 u1 = *(const uint4*)(T + (size_t)s1 * 64 + h * 8);
            uint4 u2 = *(const uint4*)(T + (size_t)s2 * 64 + h * 8);
            uint4 u3 = *(const uint4*)(T + (size_t)s3 * 64 + h * 8);
            addu4(acc, u0); addu4(acc, u1); addu4(acc, u2); addu4(acc, u3);
        }
        if (j + 8 <= m) {
            int s0 = __shfl(e, hb + j + q);
            int s1 = __shfl(e, hb + j + 4 + q);
            uint4 u0 = *(const uint4*)(T + (size_t)s0 * 64 + h * 8);
            uint4 u1 = *(const uint4*)(T + (size_t)s1 * 64 + h * 8);
            addu4(acc, u0); addu4(acc, u1);
            j += 8;
        }
        if (j + 4 <= m) {
            int s = __shfl(e, hb + j + q);
            uint4 u = *(const uint4*)(T + (size_t)s * 64 + h * 8);
            addu4(acc, u);
            j += 4;
        }
        if (j < m) {
            int jj = j + q;
            int s = __shfl(e, hb + (jj & 31));
            if (jj < m) {
                uint4 u = *(const uint4*)(T + (size_t)s * 64 + h * 8);
                addu4(acc, u);
            }
        }
    }
}

// ---------------- aggregation v2: 2 nodes per 32-lane half (4 per wave), pipelined loads ----
// Fast path (deg<=32 for both nodes, ~99.99% of nodes at Poisson(16)): issue self rows,
// both csr reads, then ALL gathers (8 or up to 16) before any accumulate — doubles
// memory-level parallelism per wave vs the 1-node/half version. Ragged slots clamp to
// the zero sentinel row T[n] (zeroed in k_prep), so no per-slot branching.
__global__ __launch_bounds__(256) void k_agg2(const unsigned short* __restrict__ T,
                                              const int* __restrict__ csr,
                                              const int* __restrict__ roffE,  // END offsets
                                              const float* __restrict__ bias,
                                              unsigned short* __restrict__ Hb, int n) {
    int lane = threadIdx.x & 63;
    int half = lane >> 5;
    int sub = lane & 31;
    int q = sub >> 3, h = sub & 7;
    int hb = half << 5;
    int w = threadIdx.x >> 6;
    int v0 = blockIdx.x * 16 + w * 4 + half * 2;
    if (v0 >= n) return;
    int v1 = v0 + 1;
    bool has1 = (v1 < n);
    int sA = (v0 == 0) ? 0 : roffE[v0 - 1];
    int eA = roffE[v0];
    int eB = has1 ? roffE[v1] : eA;
    int mA = eA - sA;
    int mB = eB - eA;
    float dvA = rsqrtf((float)(mA + 1));
    float dvB = rsqrtf((float)(mB + 1));
    float accA[8] = {0.f, 0.f, 0.f, 0.f, 0.f, 0.f, 0.f, 0.f};
    float accB[8] = {0.f, 0.f, 0.f, 0.f, 0.f, 0.f, 0.f, 0.f};
    // self rows (issued first; non-q0 lanes add zeros)
    uint4 uSA = {0u, 0u, 0u, 0u}, uSB = {0u, 0u, 0u, 0u};
    if (q == 0) {
        uSA = *(const uint4*)(T + (size_t)v0 * 64 + h * 8);
        if (has1) uSB = *(const uint4*)(T + (size_t)v1 * 64 + h * 8);
    }
    if (mA <= 32 && mB <= 32) {
        int e0 = (sub < mA) ? csr[sA + sub] : n;   // sentinel -> zero row
        int e1 = (sub < mB) ? csr[eA + sub] : n;
        // tier 1: slots 0..15 for both nodes — 8 gathers in flight
        int a0 = __shfl(e0, hb + q),      a1 = __shfl(e0, hb + 4 + q);
        int a2 = __shfl(e0, hb + 8 + q),  a3 = __shfl(e0, hb + 12 + q);
        int b0 = __shfl(e1, hb + q),      b1 = __shfl(e1, hb + 4 + q);
        int b2 = __shfl(e1, hb + 8 + q),  b3 = __shfl(e1, hb + 12 + q);
        uint4 uA0 = *(const uint4*)(T + (size_t)a0 * 64 + h * 8);
        uint4 uA1 = *(const uint4*)(T + (size_t)a1 * 64 + h * 8);
        uint4 uA2 = *(const uint4*)(T + (size_t)a2 * 64 + h * 8);
        uint4 uA3 = *(const uint4*)(T + (size_t)a3 * 64 + h * 8);
        uint4 uB0 = *(const uint4*)(T + (size_t)b0 * 64 + h * 8);
        uint4 uB1 = *(const uint4*)(T + (size_t)b1 * 64 + h * 8);
        uint4 uB2 = *(const uint4*)(T + (size_t)b2 * 64 + h * 8);
        uint4 uB3 = *(const uint4*)(T + (size_t)b3 * 64 + h * 8);
        // tier 2: slots 16..31 only when needed
        bool tA = (mA > 16), tB = (mB > 16);
        if (tA) {
            int a4 = __shfl(e0, hb + 16 + q), a5 = __shfl(e0, hb + 20 + q);
            int a6 = __shfl(e0, hb + 24 + q), a7 = __shfl(e0, hb + 28 + q);
            uint4 u4 = *(const uint4*)(T + (size_t)a4 * 64 + h * 8);
            uint4 u5 = *(const uint4*)(T + (size_t)a5 * 64 + h * 8);
            uint4 u6 = *(const uint4*)(T + (size_t)a6 * 64 + h * 8);
            uint4 u7 = *(const uint4*)(T + (size_t)a7 * 64 + h * 8);
            addu4(accA, u4); addu4(accA, u5); addu4(accA, u6); addu4(accA, u7);
        }
        if (tB) {
            int b4 = __shfl(e1, hb + 16 + q), b5 = __shfl(e1, hb + 20 + q);
            int b6 = __shfl(e1, hb + 24 + q), b7 = __shfl(e1, hb + 28 + q);
            uint4 u4 = *(const uint4*)(T + (size_t)b4 * 64 + h * 8);
            uint4 u5 = *(const uint4*)(T + (size_t)b5 * 64 + h * 8);
            uint4 u6 = *(const uint4*)(T + (size_t)b6 * 64 + h * 8);
            uint4 u7 = *(const uint4*)(T + (size_t)b7 * 64 + h * 8);
            addu4(accB, u4); addu4(accB, u5); addu4(accB, u6); addu4(accB, u7);
        }
        addu4(accA, uA0); addu4(accA, uA1); addu4(accA, uA2); addu4(accA, uA3);
        addu4(accB, uB0); addu4(accB, uB1); addu4(accB, uB2); addu4(accB, uB3);
    } else {
        agg_loop(T, csr, sA, eA, hb, sub, q, h, accA);
        agg_loop(T, csr, eA, eB, hb, sub, q, h, accB);
    }
    addu4(accA, uSA);
    addu4(accB, uSB);
#pragma unroll
    for (int i = 0; i < 8; i++) {
        accA[i] += __shfl_xor(accA[i], 8);
        accA[i] += __shfl_xor(accA[i], 16);
        accB[i] += __shfl_xor(accB[i], 8);
        accB[i] += __shfl_xor(accB[i], 16);
    }
    if (q == 0) {
        float4 b0 = *(const float4*)(bias + h * 8);
        float4 b1 = *(const float4*)(bias + h * 8 + 4);
        float bb[8] = {b0.x, b0.y, b0.z, b0.w, b1.x, b1.y, b1.z, b1.w};
        union { unsigned short hh[8]; uint4 u; } pA, pB;
#pragma unroll
        for (int i = 0; i < 8; i++) {
            float rA = dvA * accA[i] + bb[i];
            rA = (rA > 0.f) ? rA : (__expf(rA) - 1.f);
            pA.hh[i] = f2bf(rA);
            float rB = dvB * accB[i] + bb[i];
            rB = (rB > 0.f) ? rB : (__expf(rB) - 1.f);
            pB.hh[i] = f2bf(rB);
        }
        *(uint4*)(Hb + (size_t)v0 * 64 + h * 8) = pA.u;
        if (has1) *(uint4*)(Hb + (size_t)v1 * 64 + h * 8) = pB.u;
    }
}

// ---------------- launch ----------------

extern "C" void kernel_launch(void* const* d_in, const int* in_sizes, int n_in,
                              void* d_out, int out_size, void* d_ws, size_t ws_size,
                              hipStream_t stream) {
    const float* x       = (const float*)d_in[0];
    const int*   eidx    = (const int*)d_in[1];
    const float* conv0_w = (const float*)d_in[2];
    const float* conv0_b = (const float*)d_in[3];
    const float* lin0_w  = (const float*)d_in[4];
    const float* lin0_b  = (const float*)d_in[5];
    const float* conv1_w = (const float*)d_in[6];
    const float* conv1_b = (const float*)d_in[7];
    const float* lin1_w  = (const float*)d_in[8];
    const float* lin1_b  = (const float*)d_in[9];
    const float* out_w   = (const float*)d_in[10];
    const float* out_b   = (const float*)d_in[11];

    int n = in_sizes[0] / 128;
    int E = in_sizes[1] / 2;
    const int* src = eidx;
    const int* dst = eidx + E;
    int NB = (n + 255) >> 8;
    int gC = (E + CHUNK - 1) / CHUNK;

    char* wsb = (char*)d_ws;
    auto al = [](size_t v) { return (v + 4095) & ~(size_t)4095; };
    size_t o = 0;
    int*            Cmat  = (int*)(wsb + o);            o = al(o + (size_t)gC * 1024 * 4);
    int*            Omat  = (int*)(wsb + o);            o = al(o + (size_t)gC * 1024 * 4);
    int*            btot  = (int*)(wsb + o);            o = al(o + 1024 * 4);
    int*            boff  = (int*)(wsb + o);            o = al(o + 1025 * 4);
    float*          dinv  = (float*)(wsb + o);          o = al(o + (size_t)n * 4);
    int*            roff  = (int*)(wsb + o);            o = al(o + (size_t)n * 4);
    unsigned int*   part  = (unsigned int*)(wsb + o);   o = al(o + (size_t)E * 4);
    int*            csr   = (int*)(wsb + o);            o = al(o + (size_t)E * 4);
    float*          bfv   = (float*)(wsb + o);          o = al(o + 40 * 4);
    unsigned short* Wb0   = (unsigned short*)(wsb + o); o = al(o + 8192 * 2);
    unsigned short* Wb1   = (unsigned short*)(wsb + o); o = al(o + 4096 * 2);
    unsigned short* Wfb0  = (unsigned short*)(wsb + o); o = al(o + 3072 * 2);
    unsigned short* Wfb1  = (unsigned short*)(wsb + o); o = al(o + 3072 * 2);
    unsigned short* Ab    = (unsigned short*)(wsb + o); o = al(o + (size_t)(n + 1) * 64 * 2);  // +1 sentinel row
    unsigned short* Hb    = (unsigned short*)(wsb + o); o = al(o + (size_t)n * 64 * 2);
    float* O = (float*)d_out;

    int gT = (n + 63) / 64;      // MFMA gemms: 64 rows/block
    int gV2 = (n + 15) / 16;     // agg2: 16 nodes/block (4 per wave)

    // CSR build — fully deterministic offsets, no inter-block atomics, no memset
    k_count<<<gC, 256, 0, stream>>>(dst, Cmat, E);
    k_wscan<<<256, 256, 0, stream>>>(Cmat, Omat, btot, gC);
    k_bscan<<<1, 1024, 0, stream>>>(btot, boff);
    k_part2<<<gC, 256, 0, stream>>>(src, dst, Omat, boff, part, E);
    k_fill_local<<<NB, 256, 0, stream>>>(part, boff, dinv, roff, csr, n);
    k_prep<<<10, 256, 0, stream>>>(conv0_w, conv1_w, lin0_w, lin0_b, lin1_w, lin1_b,
                                   out_w, out_b, Wb0, Wb1, Wfb0, Wfb1, bfv, Ab, n);

    // layer 0
    k_gemm_128<<<gT, 256, 0, stream>>>(x, Wb0, dinv, Ab, n);
    k_agg2<<<gV2, 256, 0, stream>>>(Ab, csr, roff, conv0_b, Hb, n);
    // fused: Ab = dinv*(Hb@conv1_w), O = Hb@Wf0
    k_mid<<<gT, 256, 0, stream>>>(Hb, Wb1, Wfb0, dinv, Ab, O, n);
    // layer 1
    k_agg2<<<gV2, 256, 0, stream>>>(Ab, csr, roff, conv1_b, Hb, n);
    // final head: O += Hb @ Wf1 + bf
    k_head<<<gT, 256, 0, stream>>>(Hb, Wfb1, bfv, O, n);
}

// Round 8
// 264.640 us; speedup vs baseline: 1.1418x; 1.0425x over previous
//
#include <hip/hip_runtime.h>

#define DEVFN __device__ __forceinline__

typedef __attribute__((ext_vector_type(8))) short short8;
typedef __attribute__((ext_vector_type(4))) float float4v;

DEVFN float bf2f(unsigned short u) {
    union { unsigned int i; float f; } c;
    c.i = ((unsigned int)u) << 16;
    return c.f;
}

DEVFN unsigned short f2bf(float f) {
    union { float f; unsigned int i; } c;
    c.f = f;
    unsigned int u = c.i;
    return (unsigned short)((u + 0x7FFFu + ((u >> 16) & 1u)) >> 16);  // RNE
}

// accumulate 8 bf16 (uint4) into 8 fp32
DEVFN void addu4(float* acc, uint4 u) {
    unsigned int w[4] = {u.x, u.y, u.z, u.w};
#pragma unroll
    for (int k = 0; k < 4; k++) {
        union { unsigned int i; float f; } lo, hi;
        lo.i = w[k] << 16;
        hi.i = w[k] & 0xFFFF0000u;
        acc[2 * k]     += lo.f;
        acc[2 * k + 1] += hi.f;
    }
}

// ---------------- deterministic 2-level bucket partition ----------------

#define CHUNK 4096

__global__ __launch_bounds__(256) void k_count(const int* __restrict__ dst,
                                               int* __restrict__ Cmat, int E) {
    __shared__ int lh[1024];
    int t = threadIdx.x;
    for (int b = t; b < 1024; b += 256) lh[b] = 0;
    __syncthreads();
    int i0 = blockIdx.x * CHUNK;
    int i1 = i0 + CHUNK; if (i1 > E) i1 = E;
    for (int i = i0 + t; i < i1; i += 256) atomicAdd(&lh[dst[i] >> 8], 1);
    __syncthreads();
    int* row = Cmat + (size_t)blockIdx.x * 1024;
    for (int b = t; b < 1024; b += 256) row[b] = lh[b];
}

__global__ __launch_bounds__(256) void k_wscan(const int* __restrict__ Cmat,
                                               int* __restrict__ Omat,
                                               int* __restrict__ btot, int gC) {
    int b = (blockIdx.x * 256 + threadIdx.x) >> 6;
    int lane = threadIdx.x & 63;
    int base = 0;
    for (int c0 = 0; c0 < gC; c0 += 64) {
        int c = c0 + lane;
        int x = (c < gC) ? Cmat[(size_t)c * 1024 + b] : 0;
        int orig = x;
#pragma unroll
        for (int off = 1; off < 64; off <<= 1) {
            int y = __shfl_up(x, off);
            if (lane >= off) x += y;
        }
        if (c < gC) Omat[(size_t)c * 1024 + b] = base + x - orig;
        base += __shfl(x, 63);
    }
    if (lane == 0) btot[b] = base;
}

// k_part2 with inlined deterministic scan of btot (replaces k_bscan's boff)
__global__ __launch_bounds__(256) void k_part2(const int* __restrict__ src,
                                               const int* __restrict__ dst,
                                               const int* __restrict__ Omat,
                                               const int* __restrict__ btot,
                                               unsigned int* __restrict__ part, int E) {
    __shared__ int lb[1024];
    __shared__ int lc[1024];
    __shared__ int ws[256];
    int t = threadIdx.x;
    int b0 = btot[4 * t], b1 = btot[4 * t + 1], b2 = btot[4 * t + 2], b3 = btot[4 * t + 3];
    int s = b0 + b1 + b2 + b3;
    ws[t] = s;
    __syncthreads();
    for (int o = 1; o < 256; o <<= 1) {
        int x = (t >= o) ? ws[t - o] : 0;
        __syncthreads();
        ws[t] += x;
        __syncthreads();
    }
    int excl = ws[t] - s;   // exclusive prefix over 4t chunk
    const int* orow = Omat + (size_t)blockIdx.x * 1024;
    lb[4 * t]     = excl + orow[4 * t];
    lb[4 * t + 1] = excl + b0 + orow[4 * t + 1];
    lb[4 * t + 2] = excl + b0 + b1 + orow[4 * t + 2];
    lb[4 * t + 3] = excl + b0 + b1 + b2 + orow[4 * t + 3];
    lc[4 * t] = 0; lc[4 * t + 1] = 0; lc[4 * t + 2] = 0; lc[4 * t + 3] = 0;
    __syncthreads();
    int i0 = blockIdx.x * CHUNK;
    int i1 = i0 + CHUNK; if (i1 > E) i1 = E;
    for (int i = i0 + t; i < i1; i += 256) {
        int d = dst[i];
        int b = d >> 8;
        int r = atomicAdd(&lc[b], 1);
        part[lb[b] + r] = (unsigned int)src[i] | ((unsigned int)(d & 255) << 24);
    }
}

// k_fill_local with inlined prefix (s0 = sum btot[0..b-1], s1 = s0 + btot[b])
__global__ __launch_bounds__(256) void k_fill_local(const unsigned int* __restrict__ part,
                                                    const int* __restrict__ btot,
                                                    float* __restrict__ dinv,
                                                    int* __restrict__ roff,
                                                    int* __restrict__ csr, int n) {
    __shared__ int red[256];
    __shared__ int stb;
    __shared__ int lcnt[256];
    __shared__ int lsc[256];
    __shared__ int lcur[256];
    int b = blockIdx.x, t = threadIdx.x;
    int a0 = 0;
    for (int i = t; i < 1024; i += 256) {
        int vv = btot[i];
        if (i < b) a0 += vv;
        if (i == b) stb = vv;
    }
    red[t] = a0;
    __syncthreads();
    for (int o = 128; o > 0; o >>= 1) {
        if (t < o) red[t] += red[t + o];
        __syncthreads();
    }
    int s0 = red[0];
    int s1 = s0 + stb;
    lcnt[t] = 0;
    __syncthreads();
    for (int i = s0 + t; i < s1; i += 256) atomicAdd(&lcnt[part[i] >> 24], 1);
    __syncthreads();
    int v = lcnt[t];
    lsc[t] = v;
    __syncthreads();
    for (int o = 1; o < 256; o <<= 1) {
        int x = (t >= o) ? lsc[t - o] : 0;
        __syncthreads();
        lsc[t] += x;
        __syncthreads();
    }
    int excl = lsc[t] - v;
    int node = (b << 8) + t;
    if (node < n) {
        dinv[node] = rsqrtf((float)(v + 1));  // +1 self-loop
        roff[node] = s0 + excl + v;           // END offset
    }
    lcur[t] = s0 + excl;
    __syncthreads();
    for (int i = s0 + t; i < s1; i += 256) {
        unsigned int p = part[i];
        int pos = atomicAdd(&lcur[p >> 24], 1);
        csr[pos] = (int)(p & 0xFFFFFFu);
    }
}

// ---------------- fused prep (unchanged math) + zero sentinels Ab[n], Ab2[n] ----------------
__global__ __launch_bounds__(256) void k_prep(const float* __restrict__ W0,
                                              const float* __restrict__ W1,
                                              const float* __restrict__ lin0_w, const float* __restrict__ lin0_b,
                                              const float* __restrict__ lin1_w, const float* __restrict__ lin1_b,
                                              const float* __restrict__ out_w, const float* __restrict__ out_b,
                                              unsigned short* __restrict__ Wb0,
                                              unsigned short* __restrict__ Wb1,
                                              unsigned short* __restrict__ Wfb0,
                                              unsigned short* __restrict__ Wfb1,
                                              float* __restrict__ bfv,
                                              unsigned short* __restrict__ Ab,
                                              unsigned short* __restrict__ Ab2, int n) {
    int tid = blockIdx.x * 256 + threadIdx.x;
    if (tid < 1024) {
        int ks = tid >> 8, rem = tid & 255;
        int nt = rem >> 6, lane = rem & 63;
        int quad = lane >> 4, c = lane & 15;
        union { unsigned short h[8]; uint4 u; } p;
#pragma unroll
        for (int j = 0; j < 8; j++)
            p.h[j] = f2bf(W0[(ks * 32 + quad * 8 + j) * 64 + nt * 16 + c]);
        *(uint4*)(Wb0 + (size_t)tid * 8) = p.u;
    } else if (tid < 1536) {
        int t2 = tid - 1024;
        int ks = t2 >> 8, rem = t2 & 255;
        int nt = rem >> 6, lane = rem & 63;
        int quad = lane >> 4, c = lane & 15;
        union { unsigned short h[8]; uint4 u; } p;
#pragma unroll
        for (int j = 0; j < 8; j++)
            p.h[j] = f2bf(W1[(ks * 32 + quad * 8 + j) * 64 + nt * 16 + c]);
        *(uint4*)(Wb1 + (size_t)t2 * 8) = p.u;
    } else if (tid < 1920) {
        int t2 = tid - 1536;          // 0..383
        int ks = t2 / 192;
        int rem = t2 % 192;
        int nt = rem >> 6, lane = rem & 63;
        int quad = lane >> 4, c = lane & 15;
        int col = nt * 16 + c;
        union { unsigned short h[8]; uint4 u; } p;
#pragma unroll
        for (int j = 0; j < 8; j++) {
            unsigned short r = 0;
            if (col < 40) {
                int i = ks * 32 + quad * 8 + j;
                float a = 0.f;
                for (int k = 0; k < 64; k++) a += lin0_w[i * 64 + k] * out_w[k * 40 + col];
                r = f2bf(a);
            }
            p.h[j] = r;
        }
        *(uint4*)(Wfb0 + ((size_t)(ks * 3 + nt) * 64 + lane) * 8) = p.u;
    } else if (tid < 2304) {
        int t2 = tid - 1920;
        int ks = t2 / 192;
        int rem = t2 % 192;
        int nt = rem >> 6, lane = rem & 63;
        int quad = lane >> 4, c = lane & 15;
        int col = nt * 16 + c;
        union { unsigned short h[8]; uint4 u; } p;
#pragma unroll
        for (int j = 0; j < 8; j++) {
            unsigned short r = 0;
            if (col < 40) {
                int i = ks * 32 + quad * 8 + j;
                float a = 0.f;
                for (int k = 0; k < 64; k++) a += lin1_w[i * 64 + k] * out_w[(64 + k) * 40 + col];
                r = f2bf(a);
            }
            p.h[j] = r;
        }
        *(uint4*)(Wfb1 + ((size_t)(ks * 3 + nt) * 64 + lane) * 8) = p.u;
    } else if (tid < 2344) {
        int j = tid - 2304;
        float a = out_b[j];
        for (int k = 0; k < 64; k++) {
            a += lin0_b[k] * out_w[k * 40 + j];
            a += lin1_b[k] * out_w[(64 + k) * 40 + j];
        }
        bfv[j] = a;
    } else if (tid < 2352) {
        uint4 z = {0u, 0u, 0u, 0u};
        *(uint4*)(Ab + (size_t)n * 64 + (tid - 2344) * 8) = z;
    } else if (tid < 2360) {
        uint4 z = {0u, 0u, 0u, 0u};
        *(uint4*)(Ab2 + (size_t)n * 64 + (tid - 2352) * 8) = z;
    }
}

// ---------------- MFMA transform GEMM (layer 0, fp32 input K=128) ----------------

__global__ __launch_bounds__(256) void k_gemm_128(const float* __restrict__ A,
                                                  const unsigned short* __restrict__ Wb,
                                                  const float* __restrict__ dinv,
                                                  unsigned short* __restrict__ Cb, int n) {
    __shared__ unsigned short aLDS[64 * 144];  // 18 KB
    int t = threadIdx.x;
    int r0 = blockIdx.x * 64;
    for (int idx = t; idx < 2048; idx += 256) {   // 64 rows x 32 float4
        int r = idx >> 5;
        int k = (idx & 31) << 2;
        int gr = r0 + r; if (gr >= n) gr = n - 1;
        float4 u = *(const float4*)(A + (size_t)gr * 128 + k);
        int tile = r >> 4, m = r & 15;
        int ks = k >> 5, quad = (k >> 3) & 3, j0 = k & 7;
        int g = (tile * 4 + ks) * 4 + quad;
        union { unsigned short h[4]; uint2 u2; } pk;
        pk.h[0] = f2bf(u.x); pk.h[1] = f2bf(u.y); pk.h[2] = f2bf(u.z); pk.h[3] = f2bf(u.w);
        *(uint2*)(aLDS + g * 144 + m * 8 + j0) = pk.u2;
    }
    int lane = t & 63;
    int w = t >> 6;
    short8 bfr[4][4];
#pragma unroll
    for (int ks = 0; ks < 4; ks++)
#pragma unroll
        for (int nt = 0; nt < 4; nt++)
            bfr[ks][nt] = *(const short8*)(Wb + ((size_t)(ks * 4 + nt) * 64 + lane) * 8);
    __syncthreads();
    int quad = lane >> 4, m = lane & 15;
    short8 afr[4];
#pragma unroll
    for (int ks = 0; ks < 4; ks++)
        afr[ks] = *(const short8*)(aLDS + ((w * 4 + ks) * 4 + quad) * 144 + m * 8);
    float4v acc[4] = {};
#pragma unroll
    for (int nt = 0; nt < 4; nt++)
#pragma unroll
        for (int ks = 0; ks < 4; ks++)
            acc[nt] = __builtin_amdgcn_mfma_f32_16x16x32_bf16(afr[ks], bfr[ks][nt], acc[nt], 0, 0, 0);
    float dv[4];
#pragma unroll
    for (int reg = 0; reg < 4; reg++) {
        int gr = r0 + w * 16 + quad * 4 + reg;
        dv[reg] = (gr < n) ? dinv[gr] : 0.f;
    }
#pragma unroll
    for (int nt = 0; nt < 4; nt++)
#pragma unroll
        for (int reg = 0; reg < 4; reg++) {
            int gr = r0 + w * 16 + quad * 4 + reg;
            if (gr < n) Cb[(size_t)gr * 64 + nt * 16 + m] = f2bf(dv[reg] * acc[nt][reg]);
        }
}

// ---------------- generic per-node aggregation loop (rare deg>32 path) ----------------
DEVFN void agg_loop(const unsigned short* __restrict__ T, const int* __restrict__ csr,
                    int start, int end, int hb, int sub, int q, int h, float* acc) {
    for (int base = start; base < end; base += 32) {
        int m = end - base; if (m > 32) m = 32;
        int e = (sub < m) ? csr[base + sub] : 0;
        int j = 0;
        for (; j + 16 <= m; j += 16) {
            int s0 = __shfl(e, hb + j + q);
            int s1 = __shfl(e, hb + j + 4 + q);
            int s2 = __shfl(e, hb + j + 8 + q);
            int s3 = __shfl(e, hb + j + 12 + q);
            uint4 u0 = *(const uint4*)(T + (size_t)s0 * 64 + h * 8);
            uint4 u1 = *(const uint4*)(T + (size_t)s1 * 64 + h * 8);
            uint4 u2 = *(const uint4*)(T + (size_t)s2 * 64 + h * 8);
            uint4 u3 = *(const uint4*)(T + (size_t)s3 * 64 + h * 8);
            addu4(acc, u0); addu4(acc, u1); addu4(acc, u2); addu4(acc, u3);
        }
        if (j + 8 <= m) {
            int s0 = __shfl(e, hb + j + q);
            int s1 = __shfl(e, hb + j + 4 + q);
            uint4 u0 = *(const uint4*)(T + (size_t)s0 * 64 + h * 8);
            uint4 u1 = *(const uint4*)(T + (size_t)s1 * 64 + h * 8);
            addu4(acc, u0); addu4(acc, u1);
            j += 8;
        }
        if (j + 4 <= m) {
            int s = __shfl(e, hb + j + q);
            uint4 u = *(const uint4*)(T + (size_t)s * 64 + h * 8);
            addu4(acc, u);
            j += 4;
        }
        if (j < m) {
            int jj = j + q;
            int s = __shfl(e, hb + (jj & 31));
            if (jj < m) {
                uint4 u = *(const uint4*)(T + (size_t)s * 64 + h * 8);
                addu4(acc, u);
            }
        }
    }
}

// gather for the node pair (v0, v0+1) — identical arithmetic to k_agg2
DEVFN void gather2(const unsigned short* __restrict__ T, const int* __restrict__ csr,
                   const int* __restrict__ roffE, int v0, int n,
                   int hb, int sub, int q, int h,
                   float* accA, float* accB, float& dvA, float& dvB) {
    int v1 = v0 + 1;
    bool has1 = (v1 < n);
    int sA = (v0 == 0) ? 0 : roffE[v0 - 1];
    int eA = roffE[v0];
    int eB = has1 ? roffE[v1] : eA;
    int mA = eA - sA;
    int mB = eB - eA;
    dvA = rsqrtf((float)(mA + 1));
    dvB = rsqrtf((float)(mB + 1));
    uint4 uSA = {0u, 0u, 0u, 0u}, uSB = {0u, 0u, 0u, 0u};
    if (q == 0) {
        uSA = *(const uint4*)(T + (size_t)v0 * 64 + h * 8);
        if (has1) uSB = *(const uint4*)(T + (size_t)v1 * 64 + h * 8);
    }
    if (mA <= 32 && mB <= 32) {
        int e0 = (sub < mA) ? csr[sA + sub] : n;   // sentinel -> zero row
        int e1 = (sub < mB) ? csr[eA + sub] : n;
        int a0 = __shfl(e0, hb + q),      a1 = __shfl(e0, hb + 4 + q);
        int a2 = __shfl(e0, hb + 8 + q),  a3 = __shfl(e0, hb + 12 + q);
        int b0 = __shfl(e1, hb + q),      b1 = __shfl(e1, hb + 4 + q);
        int b2 = __shfl(e1, hb + 8 + q),  b3 = __shfl(e1, hb + 12 + q);
        uint4 uA0 = *(const uint4*)(T + (size_t)a0 * 64 + h * 8);
        uint4 uA1 = *(const uint4*)(T + (size_t)a1 * 64 + h * 8);
        uint4 uA2 = *(const uint4*)(T + (size_t)a2 * 64 + h * 8);
        uint4 uA3 = *(const uint4*)(T + (size_t)a3 * 64 + h * 8);
        uint4 uB0 = *(const uint4*)(T + (size_t)b0 * 64 + h * 8);
        uint4 uB1 = *(const uint4*)(T + (size_t)b1 * 64 + h * 8);
        uint4 uB2 = *(const uint4*)(T + (size_t)b2 * 64 + h * 8);
        uint4 uB3 = *(const uint4*)(T + (size_t)b3 * 64 + h * 8);
        bool tA = (mA > 16), tB = (mB > 16);
        if (tA) {
            int a4 = __shfl(e0, hb + 16 + q), a5 = __shfl(e0, hb + 20 + q);
            int a6 = __shfl(e0, hb + 24 + q), a7 = __shfl(e0, hb + 28 + q);
            uint4 u4 = *(const uint4*)(T + (size_t)a4 * 64 + h * 8);
            uint4 u5 = *(const uint4*)(T + (size_t)a5 * 64 + h * 8);
            uint4 u6 = *(const uint4*)(T + (size_t)a6 * 64 + h * 8);
            uint4 u7 = *(const uint4*)(T + (size_t)a7 * 64 + h * 8);
            addu4(accA, u4); addu4(accA, u5); addu4(accA, u6); addu4(accA, u7);
        }
        if (tB) {
            int b4 = __shfl(e1, hb + 16 + q), b5 = __shfl(e1, hb + 20 + q);
            int b6 = __shfl(e1, hb + 24 + q), b7 = __shfl(e1, hb + 28 + q);
            uint4 u4 = *(const uint4*)(T + (size_t)b4 * 64 + h * 8);
            uint4 u5 = *(const uint4*)(T + (size_t)b5 * 64 + h * 8);
            uint4 u6 = *(const uint4*)(T + (size_t)b6 * 64 + h * 8);
            uint4 u7 = *(const uint4*)(T + (size_t)b7 * 64 + h * 8);
            addu4(accB, u4); addu4(accB, u5); addu4(accB, u6); addu4(accB, u7);
        }
        addu4(accA, uA0); addu4(accA, uA1); addu4(accA, uA2); addu4(accA, uA3);
        addu4(accB, uB0); addu4(accB, uB1); addu4(accB, uB2); addu4(accB, uB3);
    } else {
        agg_loop(T, csr, sA, eA, hb, sub, q, h, accA);
        agg_loop(T, csr, eA, eB, hb, sub, q, h, accB);
    }
    addu4(accA, uSA);
    addu4(accB, uSB);
}

// ---------------- fused agg pass 1 + mid GEMMs ----------------
// Block = 16 nodes (4 waves x 2 halves x 2 nodes). After gather + elu, the 16 bf16
// H-rows are staged in 2.3 KB LDS as a 16x64 MFMA A-tile (same group layout as k_mid,
// tile=0). MFMA col-tiles wave-split: w0: conv1 nt0,1; w1: conv1 nt2,3; w2: head0 nt0,1;
// w3: head0 nt2. Eliminates the Hb global round-trip entirely.
__global__ __launch_bounds__(256) void k_aggmid(const unsigned short* __restrict__ T,    // Ab (dinv-folded)
                                                const int* __restrict__ csr,
                                                const int* __restrict__ roffE,
                                                const float* __restrict__ bias,          // conv0_b
                                                const unsigned short* __restrict__ WbG,  // conv1 2ks x 4nt
                                                const unsigned short* __restrict__ WbH,  // head0 2ks x 3nt
                                                const float* __restrict__ dinv,
                                                unsigned short* __restrict__ Ab2,        // layer-1 T (dinv-folded)
                                                float* __restrict__ O, int n) {
    __shared__ unsigned short aLDS[8 * 144];   // 2.3 KB
    int t = threadIdx.x;
    int lane = t & 63, w = t >> 6;
    int half = lane >> 5, sub = lane & 31;
    int q = sub >> 3, h = sub & 7;
    int hb = half << 5;
    int lv = w * 4 + half * 2;
    int v0 = blockIdx.x * 16 + lv;
    bool act = (v0 < n);
    float accA[8] = {0.f, 0.f, 0.f, 0.f, 0.f, 0.f, 0.f, 0.f};
    float accB[8] = {0.f, 0.f, 0.f, 0.f, 0.f, 0.f, 0.f, 0.f};
    float dvA = 0.f, dvB = 0.f;
    if (act) gather2(T, csr, roffE, v0, n, hb, sub, q, h, accA, accB, dvA, dvB);
#pragma unroll
    for (int i = 0; i < 8; i++) {
        accA[i] += __shfl_xor(accA[i], 8);
        accA[i] += __shfl_xor(accA[i], 16);
        accB[i] += __shfl_xor(accB[i], 8);
        accB[i] += __shfl_xor(accB[i], 16);
    }
    if (act && q == 0) {
        float4 b0 = *(const float4*)(bias + h * 8);
        float4 b1 = *(const float4*)(bias + h * 8 + 4);
        float bb[8] = {b0.x, b0.y, b0.z, b0.w, b1.x, b1.y, b1.z, b1.w};
        union { unsigned short hh[8]; uint4 u; } pA, pB;
#pragma unroll
        for (int i = 0; i < 8; i++) {
            float rA = dvA * accA[i] + bb[i];
            rA = (rA > 0.f) ? rA : (__expf(rA) - 1.f);
            pA.hh[i] = f2bf(rA);
            float rB = dvB * accB[i] + bb[i];
            rB = (rB > 0.f) ? rB : (__expf(rB) - 1.f);
            pB.hh[i] = f2bf(rB);
        }
        // group index == h (feature block f/8), row offset == local node
        *(uint4*)(aLDS + h * 144 + lv * 8) = pA.u;
        if (v0 + 1 < n) *(uint4*)(aLDS + h * 144 + (lv + 1) * 8) = pB.u;
    }
    __syncthreads();
    // ---- MFMA phase ----
    int quad = lane >> 4, m = lane & 15;
    short8 afr[2];
#pragma unroll
    for (int ks = 0; ks < 2; ks++)
        afr[ks] = *(const short8*)(aLDS + (ks * 4 + quad) * 144 + m * 8);
    int r0 = blockIdx.x * 16;
    if (w < 2) {
        // conv1 tiles nt0 = w*2, w*2+1 -> Ab2 (dinv-folded)
        int nt0 = w * 2;
        float4v a0 = {}, a1 = {};
#pragma unroll
        for (int ks = 0; ks < 2; ks++) {
            short8 bf0 = *(const short8*)(WbG + ((size_t)(ks * 4 + nt0) * 64 + lane) * 8);
            short8 bf1 = *(const short8*)(WbG + ((size_t)(ks * 4 + nt0 + 1) * 64 + lane) * 8);
            a0 = __builtin_amdgcn_mfma_f32_16x16x32_bf16(afr[ks], bf0, a0, 0, 0, 0);
            a1 = __builtin_amdgcn_mfma_f32_16x16x32_bf16(afr[ks], bf1, a1, 0, 0, 0);
        }
#pragma unroll
        for (int reg = 0; reg < 4; reg++) {
            int gr = r0 + quad * 4 + reg;
            if (gr < n) {
                float dv = dinv[gr];
                Ab2[(size_t)gr * 64 + nt0 * 16 + m]       = f2bf(dv * a0[reg]);
                Ab2[(size_t)gr * 64 + (nt0 + 1) * 16 + m] = f2bf(dv * a1[reg]);
            }
        }
    } else {
        // head0 tiles: w=2 -> nt 0,1 ; w=3 -> nt 2
        int nt0 = (w - 2) * 2;
        int ntc = (w == 2) ? 2 : 1;
        float4v a0 = {}, a1 = {};
#pragma unroll
        for (int ks = 0; ks < 2; ks++) {
            short8 bf0 = *(const short8*)(WbH + ((size_t)(ks * 3 + nt0) * 64 + lane) * 8);
            a0 = __builtin_amdgcn_mfma_f32_16x16x32_bf16(afr[ks], bf0, a0, 0, 0, 0);
        }
        if (ntc == 2) {
#pragma unroll
            for (int ks = 0; ks < 2; ks++) {
                short8 bf1 = *(const short8*)(WbH + ((size_t)(ks * 3 + nt0 + 1) * 64 + lane) * 8);
                a1 = __builtin_amdgcn_mfma_f32_16x16x32_bf16(afr[ks], bf1, a1, 0, 0, 0);
            }
        }
        int col0 = nt0 * 16 + m;
        if (col0 < 40) {
#pragma unroll
            for (int reg = 0; reg < 4; reg++) {
                int gr = r0 + quad * 4 + reg;
                if (gr < n) O[(size_t)gr * 40 + col0] = a0[reg];
            }
        }
        if (ntc == 2) {
            int col1 = (nt0 + 1) * 16 + m;
            if (col1 < 40) {
#pragma unroll
                for (int reg = 0; reg < 4; reg++) {
                    int gr = r0 + quad * 4 + reg;
                    if (gr < n) O[(size_t)gr * 40 + col1] = a1[reg];
                }
            }
        }
    }
}

// ---------------- fused agg pass 2 + final head: O += H1 @ Wf1 + bfv ----------------
__global__ __launch_bounds__(256) void k_agghead(const unsigned short* __restrict__ T,   // Ab2
                                                 const int* __restrict__ csr,
                                                 const int* __restrict__ roffE,
                                                 const float* __restrict__ bias,         // conv1_b
                                                 const unsigned short* __restrict__ Wfb, // head1 2ks x 3nt
                                                 const float* __restrict__ bfv,
                                                 float* __restrict__ O, int n) {
    __shared__ unsigned short aLDS[8 * 144];
    int t = threadIdx.x;
    int lane = t & 63, w = t >> 6;
    int half = lane >> 5, sub = lane & 31;
    int q = sub >> 3, h = sub & 7;
    int hb = half << 5;
    int lv = w * 4 + half * 2;
    int v0 = blockIdx.x * 16 + lv;
    bool act = (v0 < n);
    float accA[8] = {0.f, 0.f, 0.f, 0.f, 0.f, 0.f, 0.f, 0.f};
    float accB[8] = {0.f, 0.f, 0.f, 0.f, 0.f, 0.f, 0.f, 0.f};
    float dvA = 0.f, dvB = 0.f;
    if (act) gather2(T, csr, roffE, v0, n, hb, sub, q, h, accA, accB, dvA, dvB);
#pragma unroll
    for (int i = 0; i < 8; i++) {
        accA[i] += __shfl_xor(accA[i], 8);
        accA[i] += __shfl_xor(accA[i], 16);
        accB[i] += __shfl_xor(accB[i], 8);
        accB[i] += __shfl_xor(accB[i], 16);
    }
    if (act && q == 0) {
        float4 b0 = *(const float4*)(bias + h * 8);
        float4 b1 = *(const float4*)(bias + h * 8 + 4);
        float bb[8] = {b0.x, b0.y, b0.z, b0.w, b1.x, b1.y, b1.z, b1.w};
        union { unsigned short hh[8]; uint4 u; } pA, pB;
#pragma unroll
        for (int i = 0; i < 8; i++) {
            float rA = dvA * accA[i] + bb[i];
            rA = (rA > 0.f) ? rA : (__expf(rA) - 1.f);
            pA.hh[i] = f2bf(rA);
            float rB = dvB * accB[i] + bb[i];
            rB = (rB > 0.f) ? rB : (__expf(rB) - 1.f);
            pB.hh[i] = f2bf(rB);
        }
        *(uint4*)(aLDS + h * 144 + lv * 8) = pA.u;
        if (v0 + 1 < n) *(uint4*)(aLDS + h * 144 + (lv + 1) * 8) = pB.u;
    }
    __syncthreads();
    int quad = lane >> 4, m = lane & 15;
    short8 afr[2];
#pragma unroll
    for (int ks = 0; ks < 2; ks++)
        afr[ks] = *(const short8*)(aLDS + (ks * 4 + quad) * 144 + m * 8);
    int r0 = blockIdx.x * 16;
    if (w < 3) {
        float4v a0 = {};
#pragma unroll
        for (int ks = 0; ks < 2; ks++) {
            short8 bf0 = *(const short8*)(Wfb + ((size_t)(ks * 3 + w) * 64 + lane) * 8);
            a0 = __builtin_amdgcn_mfma_f32_16x16x32_bf16(afr[ks], bf0, a0, 0, 0, 0);
        }
        int col = w * 16 + m;
        if (col < 40) {
            float bb = bfv[col];
#pragma unroll
            for (int reg = 0; reg < 4; reg++) {
                int gr = r0 + quad * 4 + reg;
                if (gr < n) {
                    size_t p = (size_t)gr * 40 + col;
                    O[p] = O[p] + a0[reg] + bb;
                }
            }
        }
    }
}

// ---------------- launch ----------------

extern "C" void kernel_launch(void* const* d_in, const int* in_sizes, int n_in,
                              void* d_out, int out_size, void* d_ws, size_t ws_size,
                              hipStream_t stream) {
    const float* x       = (const float*)d_in[0];
    const int*   eidx    = (const int*)d_in[1];
    const float* conv0_w = (const float*)d_in[2];
    const float* conv0_b = (const float*)d_in[3];
    const float* lin0_w  = (const float*)d_in[4];
    const float* lin0_b  = (const float*)d_in[5];
    const float* conv1_w = (const float*)d_in[6];
    const float* conv1_b = (const float*)d_in[7];
    const float* lin1_w  = (const float*)d_in[8];
    const float* lin1_b  = (const float*)d_in[9];
    const float* out_w   = (const float*)d_in[10];
    const float* out_b   = (const float*)d_in[11];

    int n = in_sizes[0] / 128;
    int E = in_sizes[1] / 2;
    const int* src = eidx;
    const int* dst = eidx + E;
    int NB = (n + 255) >> 8;
    int gC = (E + CHUNK - 1) / CHUNK;

    char* wsb = (char*)d_ws;
    auto al = [](size_t v) { return (v + 4095) & ~(size_t)4095; };
    size_t o = 0;
    int*            Cmat  = (int*)(wsb + o);            o = al(o + (size_t)gC * 1024 * 4);
    int*            Omat  = (int*)(wsb + o);            o = al(o + (size_t)gC * 1024 * 4);
    int*            btot  = (int*)(wsb + o);            o = al(o + 1024 * 4);
    float*          dinv  = (float*)(wsb + o);          o = al(o + (size_t)n * 4);
    int*            roff  = (int*)(wsb + o);            o = al(o + (size_t)n * 4);
    unsigned int*   part  = (unsigned int*)(wsb + o);   o = al(o + (size_t)E * 4);
    int*            csr   = (int*)(wsb + o);            o = al(o + (size_t)E * 4);
    float*          bfv   = (float*)(wsb + o);          o = al(o + 40 * 4);
    unsigned short* Wb0   = (unsigned short*)(wsb + o); o = al(o + 8192 * 2);
    unsigned short* Wb1   = (unsigned short*)(wsb + o); o = al(o + 4096 * 2);
    unsigned short* Wfb0  = (unsigned short*)(wsb + o); o = al(o + 3072 * 2);
    unsigned short* Wfb1  = (unsigned short*)(wsb + o); o = al(o + 3072 * 2);
    unsigned short* Ab    = (unsigned short*)(wsb + o); o = al(o + (size_t)(n + 1) * 64 * 2);  // +1 sentinel
    unsigned short* Ab2   = (unsigned short*)(wsb + o); o = al(o + (size_t)(n + 1) * 64 * 2);  // +1 sentinel
    float* O = (float*)d_out;

    int gT = (n + 63) / 64;      // layer-0 MFMA gemm: 64 rows/block
    int gV2 = (n + 15) / 16;     // fused agg kernels: 16 nodes/block

    // CSR build — deterministic; bscan folded into part2/fill_local
    k_count<<<gC, 256, 0, stream>>>(dst, Cmat, E);
    k_wscan<<<256, 256, 0, stream>>>(Cmat, Omat, btot, gC);
    k_part2<<<gC, 256, 0, stream>>>(src, dst, Omat, btot, part, E);
    k_fill_local<<<NB, 256, 0, stream>>>(part, btot, dinv, roff, csr, n);
    k_prep<<<10, 256, 0, stream>>>(conv0_w, conv1_w, lin0_w, lin0_b, lin1_w, lin1_b,
                                   out_w, out_b, Wb0, Wb1, Wfb0, Wfb1, bfv, Ab, Ab2, n);

    // layer 0 transform
    k_gemm_128<<<gT, 256, 0, stream>>>(x, Wb0, dinv, Ab, n);
    // fused: agg pass1 + (Ab2 = dinv*(H0@conv1_w), O = H0@Wf0)
    k_aggmid<<<gV2, 256, 0, stream>>>(Ab, csr, roff, conv0_b, Wb1, Wfb0, dinv, Ab2, O, n);
    // fused: agg pass2 + (O += H1@Wf1 + bfv)
    k_agghead<<<gV2, 256, 0, stream>>>(Ab2, csr, roff, conv1_b, Wfb1, bfv, O, n);
}

// Round 9
// 256.302 us; speedup vs baseline: 1.1789x; 1.0325x over previous
//
#include <hip/hip_runtime.h>

#define DEVFN __device__ __forceinline__

typedef __attribute__((ext_vector_type(8))) short short8;
typedef __attribute__((ext_vector_type(4))) float float4v;

DEVFN float bf2f(unsigned short u) {
    union { unsigned int i; float f; } c;
    c.i = ((unsigned int)u) << 16;
    return c.f;
}

DEVFN unsigned short f2bf(float f) {
    union { float f; unsigned int i; } c;
    c.f = f;
    unsigned int u = c.i;
    return (unsigned short)((u + 0x7FFFu + ((u >> 16) & 1u)) >> 16);  // RNE
}

// accumulate 8 bf16 (uint4) into 8 fp32
DEVFN void addu4(float* acc, uint4 u) {
    unsigned int w[4] = {u.x, u.y, u.z, u.w};
#pragma unroll
    for (int k = 0; k < 4; k++) {
        union { unsigned int i; float f; } lo, hi;
        lo.i = w[k] << 16;
        hi.i = w[k] & 0xFFFF0000u;
        acc[2 * k]     += lo.f;
        acc[2 * k + 1] += hi.f;
    }
}

#define CHUNK 4096

// ---------------- single-pass bucketed scatter (strided buckets, atomic range reserve) ----
// Bucket b = dst>>8 occupies part[b*STRIDE .. b*STRIDE+gcnt[b]).  Offsets within a bucket
// are nondeterministic across blocks (atomic reserve) — same class of summation-order
// perturbation as the pre-existing within-block atomic cursor; tolerance-safe.
__global__ __launch_bounds__(256) void k_scat(const int* __restrict__ src,
                                              const int* __restrict__ dst,
                                              int* __restrict__ gcnt,
                                              unsigned int* __restrict__ part,
                                              int E, int STRIDE) {
    __shared__ int lh[1024];
    __shared__ int lb[1024];
    int t = threadIdx.x;
    for (int b = t; b < 1024; b += 256) lh[b] = 0;
    __syncthreads();
    int i0 = blockIdx.x * CHUNK;
    int d[16];
#pragma unroll
    for (int k = 0; k < 16; k++) {
        int idx = i0 + k * 256 + t;
        d[k] = (idx < E) ? dst[idx] : -1;
        if (d[k] >= 0) atomicAdd(&lh[d[k] >> 8], 1);
    }
    __syncthreads();
    for (int b = t; b < 1024; b += 256) {
        int c = lh[b];
        if (c > 0) lb[b] = b * STRIDE + atomicAdd(&gcnt[b], c);
        lh[b] = 0;  // reuse as cursor
    }
    __syncthreads();
#pragma unroll
    for (int k = 0; k < 16; k++) {
        if (d[k] >= 0) {
            int idx = i0 + k * 256 + t;
            int s = src[idx];
            int b = d[k] >> 8;
            int r = atomicAdd(&lh[b], 1);
            part[lb[b] + r] = (unsigned int)s | ((unsigned int)(d[k] & 255) << 24);
        }
    }
}

// ---------------- per-bucket CSR fill (node-local histogram + scan), strided csr ---------
__global__ __launch_bounds__(256) void k_fill2(const unsigned int* __restrict__ part,
                                               const int* __restrict__ gcnt,
                                               float* __restrict__ dinv,
                                               int* __restrict__ roff,   // END offsets
                                               int* __restrict__ csr, int n, int STRIDE) {
    __shared__ int lcnt[256];
    __shared__ int lsc[256];
    __shared__ int lcur[256];
    int b = blockIdx.x, t = threadIdx.x;
    int cnt = gcnt[b];
    int s0 = b * STRIDE;
    lcnt[t] = 0;
    __syncthreads();
    for (int i = t; i < cnt; i += 256) atomicAdd(&lcnt[part[s0 + i] >> 24], 1);
    __syncthreads();
    int v = lcnt[t];
    lsc[t] = v;
    __syncthreads();
    for (int o = 1; o < 256; o <<= 1) {
        int x = (t >= o) ? lsc[t - o] : 0;
        __syncthreads();
        lsc[t] += x;
        __syncthreads();
    }
    int excl = lsc[t] - v;
    int node = (b << 8) + t;
    if (node < n) {
        dinv[node] = rsqrtf((float)(v + 1));  // +1 self-loop
        roff[node] = s0 + excl + v;           // END offset (bucket-strided space)
    }
    lcur[t] = s0 + excl;
    __syncthreads();
    for (int i = t; i < cnt; i += 256) {
        unsigned int p = part[s0 + i];
        int pos = atomicAdd(&lcur[p >> 24], 1);
        csr[pos] = (int)(p & 0xFFFFFFu);
    }
}

// ---------------- fused prep (unchanged math) + zero sentinels Ab[n], Ab2[n] ----------------
__global__ __launch_bounds__(256) void k_prep(const float* __restrict__ W0,
                                              const float* __restrict__ W1,
                                              const float* __restrict__ lin0_w, const float* __restrict__ lin0_b,
                                              const float* __restrict__ lin1_w, const float* __restrict__ lin1_b,
                                              const float* __restrict__ out_w, const float* __restrict__ out_b,
                                              unsigned short* __restrict__ Wb0,
                                              unsigned short* __restrict__ Wb1,
                                              unsigned short* __restrict__ Wfb0,
                                              unsigned short* __restrict__ Wfb1,
                                              float* __restrict__ bfv,
                                              unsigned short* __restrict__ Ab,
                                              unsigned short* __restrict__ Ab2, int n) {
    int tid = blockIdx.x * 256 + threadIdx.x;
    if (tid < 1024) {
        int ks = tid >> 8, rem = tid & 255;
        int nt = rem >> 6, lane = rem & 63;
        int quad = lane >> 4, c = lane & 15;
        union { unsigned short h[8]; uint4 u; } p;
#pragma unroll
        for (int j = 0; j < 8; j++)
            p.h[j] = f2bf(W0[(ks * 32 + quad * 8 + j) * 64 + nt * 16 + c]);
        *(uint4*)(Wb0 + (size_t)tid * 8) = p.u;
    } else if (tid < 1536) {
        int t2 = tid - 1024;
        int ks = t2 >> 8, rem = t2 & 255;
        int nt = rem >> 6, lane = rem & 63;
        int quad = lane >> 4, c = lane & 15;
        union { unsigned short h[8]; uint4 u; } p;
#pragma unroll
        for (int j = 0; j < 8; j++)
            p.h[j] = f2bf(W1[(ks * 32 + quad * 8 + j) * 64 + nt * 16 + c]);
        *(uint4*)(Wb1 + (size_t)t2 * 8) = p.u;
    } else if (tid < 1920) {
        int t2 = tid - 1536;          // 0..383
        int ks = t2 / 192;
        int rem = t2 % 192;
        int nt = rem >> 6, lane = rem & 63;
        int quad = lane >> 4, c = lane & 15;
        int col = nt * 16 + c;
        union { unsigned short h[8]; uint4 u; } p;
#pragma unroll
        for (int j = 0; j < 8; j++) {
            unsigned short r = 0;
            if (col < 40) {
                int i = ks * 32 + quad * 8 + j;
                float a = 0.f;
                for (int k = 0; k < 64; k++) a += lin0_w[i * 64 + k] * out_w[k * 40 + col];
                r = f2bf(a);
            }
            p.h[j] = r;
        }
        *(uint4*)(Wfb0 + ((size_t)(ks * 3 + nt) * 64 + lane) * 8) = p.u;
    } else if (tid < 2304) {
        int t2 = tid - 1920;
        int ks = t2 / 192;
        int rem = t2 % 192;
        int nt = rem >> 6, lane = rem & 63;
        int quad = lane >> 4, c = lane & 15;
        int col = nt * 16 + c;
        union { unsigned short h[8]; uint4 u; } p;
#pragma unroll
        for (int j = 0; j < 8; j++) {
            unsigned short r = 0;
            if (col < 40) {
                int i = ks * 32 + quad * 8 + j;
                float a = 0.f;
                for (int k = 0; k < 64; k++) a += lin1_w[i * 64 + k] * out_w[(64 + k) * 40 + col];
                r = f2bf(a);
            }
            p.h[j] = r;
        }
        *(uint4*)(Wfb1 + ((size_t)(ks * 3 + nt) * 64 + lane) * 8) = p.u;
    } else if (tid < 2344) {
        int j = tid - 2304;
        float a = out_b[j];
        for (int k = 0; k < 64; k++) {
            a += lin0_b[k] * out_w[k * 40 + j];
            a += lin1_b[k] * out_w[(64 + k) * 40 + j];
        }
        bfv[j] = a;
    } else if (tid < 2352) {
        uint4 z = {0u, 0u, 0u, 0u};
        *(uint4*)(Ab + (size_t)n * 64 + (tid - 2344) * 8) = z;
    } else if (tid < 2360) {
        uint4 z = {0u, 0u, 0u, 0u};
        *(uint4*)(Ab2 + (size_t)n * 64 + (tid - 2352) * 8) = z;
    }
}

// ---------------- MFMA transform GEMM (layer 0, fp32 input K=128) ----------------

__global__ __launch_bounds__(256) void k_gemm_128(const float* __restrict__ A,
                                                  const unsigned short* __restrict__ Wb,
                                                  const float* __restrict__ dinv,
                                                  unsigned short* __restrict__ Cb, int n) {
    __shared__ unsigned short aLDS[64 * 144];  // 18 KB
    int t = threadIdx.x;
    int r0 = blockIdx.x * 64;
    for (int idx = t; idx < 2048; idx += 256) {   // 64 rows x 32 float4
        int r = idx >> 5;
        int k = (idx & 31) << 2;
        int gr = r0 + r; if (gr >= n) gr = n - 1;
        float4 u = *(const float4*)(A + (size_t)gr * 128 + k);
        int tile = r >> 4, m = r & 15;
        int ks = k >> 5, quad = (k >> 3) & 3, j0 = k & 7;
        int g = (tile * 4 + ks) * 4 + quad;
        union { unsigned short h[4]; uint2 u2; } pk;
        pk.h[0] = f2bf(u.x); pk.h[1] = f2bf(u.y); pk.h[2] = f2bf(u.z); pk.h[3] = f2bf(u.w);
        *(uint2*)(aLDS + g * 144 + m * 8 + j0) = pk.u2;
    }
    int lane = t & 63;
    int w = t >> 6;
    short8 bfr[4][4];
#pragma unroll
    for (int ks = 0; ks < 4; ks++)
#pragma unroll
        for (int nt = 0; nt < 4; nt++)
            bfr[ks][nt] = *(const short8*)(Wb + ((size_t)(ks * 4 + nt) * 64 + lane) * 8);
    __syncthreads();
    int quad = lane >> 4, m = lane & 15;
    short8 afr[4];
#pragma unroll
    for (int ks = 0; ks < 4; ks++)
        afr[ks] = *(const short8*)(aLDS + ((w * 4 + ks) * 4 + quad) * 144 + m * 8);
    float4v acc[4] = {};
#pragma unroll
    for (int nt = 0; nt < 4; nt++)
#pragma unroll
        for (int ks = 0; ks < 4; ks++)
            acc[nt] = __builtin_amdgcn_mfma_f32_16x16x32_bf16(afr[ks], bfr[ks][nt], acc[nt], 0, 0, 0);
    float dv[4];
#pragma unroll
    for (int reg = 0; reg < 4; reg++) {
        int gr = r0 + w * 16 + quad * 4 + reg;
        dv[reg] = (gr < n) ? dinv[gr] : 0.f;
    }
#pragma unroll
    for (int nt = 0; nt < 4; nt++)
#pragma unroll
        for (int reg = 0; reg < 4; reg++) {
            int gr = r0 + w * 16 + quad * 4 + reg;
            if (gr < n) Cb[(size_t)gr * 64 + nt * 16 + m] = f2bf(dv[reg] * acc[nt][reg]);
        }
}

// ---------------- generic per-node aggregation loop (rare deg>32 path) ----------------
DEVFN void agg_loop(const unsigned short* __restrict__ T, const int* __restrict__ csr,
                    int start, int end, int hb, int sub, int q, int h, float* acc) {
    for (int base = start; base < end; base += 32) {
        int m = end - base; if (m > 32) m = 32;
        int e = (sub < m) ? csr[base + sub] : 0;
        int j = 0;
        for (; j + 16 <= m; j += 16) {
            int s0 = __shfl(e, hb + j + q);
            int s1 = __shfl(e, hb + j + 4 + q);
            int s2 = __shfl(e, hb + j + 8 + q);
            int s3 = __shfl(e, hb + j + 12 + q);
            uint4 u0 = *(const uint4*)(T + (size_t)s0 * 64 + h * 8);
            uint4 u1 = *(const uint4*)(T + (size_t)s1 * 64 + h * 8);
            uint4 u2 = *(const uint4*)(T + (size_t)s2 * 64 + h * 8);
            uint4 u3 = *(const uint4*)(T + (size_t)s3 * 64 + h * 8);
            addu4(acc, u0); addu4(acc, u1); addu4(acc, u2); addu4(acc, u3);
        }
        if (j + 8 <= m) {
            int s0 = __shfl(e, hb + j + q);
            int s1 = __shfl(e, hb + j + 4 + q);
            uint4 u0 = *(const uint4*)(T + (size_t)s0 * 64 + h * 8);
            uint4 u1 = *(const uint4*)(T + (size_t)s1 * 64 + h * 8);
            addu4(acc, u0); addu4(acc, u1);
            j += 8;
        }
        if (j + 4 <= m) {
            int s = __shfl(e, hb + j + q);
            uint4 u = *(const uint4*)(T + (size_t)s * 64 + h * 8);
            addu4(acc, u);
            j += 4;
        }
        if (j < m) {
            int jj = j + q;
            int s = __shfl(e, hb + (jj & 31));
            if (jj < m) {
                uint4 u = *(const uint4*)(T + (size_t)s * 64 + h * 8);
                addu4(acc, u);
            }
        }
    }
}

// gather for the node pair (v0, v0+1); bucket-strided CSR space.
// v0 is even and 16-aligned blocks never straddle a 256-node bucket, so v1 shares v0's bucket.
DEVFN void gather2(const unsigned short* __restrict__ T, const int* __restrict__ csr,
                   const int* __restrict__ roffE, int v0, int n, int stride,
                   int hb, int sub, int q, int h,
                   float* accA, float* accB, float& dvA, float& dvB) {
    int v1 = v0 + 1;
    bool has1 = (v1 < n);
    int sA = ((v0 & 255) == 0) ? (v0 >> 8) * stride : roffE[v0 - 1];
    int eA = roffE[v0];
    int eB = has1 ? roffE[v1] : eA;
    int mA = eA - sA;
    int mB = eB - eA;
    dvA = rsqrtf((float)(mA + 1));
    dvB = rsqrtf((float)(mB + 1));
    uint4 uSA = {0u, 0u, 0u, 0u}, uSB = {0u, 0u, 0u, 0u};
    if (q == 0) {
        uSA = *(const uint4*)(T + (size_t)v0 * 64 + h * 8);
        if (has1) uSB = *(const uint4*)(T + (size_t)v1 * 64 + h * 8);
    }
    if (mA <= 32 && mB <= 32) {
        int e0 = (sub < mA) ? csr[sA + sub] : n;   // sentinel -> zero row
        int e1 = (sub < mB) ? csr[eA + sub] : n;
        int a0 = __shfl(e0, hb + q),      a1 = __shfl(e0, hb + 4 + q);
        int a2 = __shfl(e0, hb + 8 + q),  a3 = __shfl(e0, hb + 12 + q);
        int b0 = __shfl(e1, hb + q),      b1 = __shfl(e1, hb + 4 + q);
        int b2 = __shfl(e1, hb + 8 + q),  b3 = __shfl(e1, hb + 12 + q);
        uint4 uA0 = *(const uint4*)(T + (size_t)a0 * 64 + h * 8);
        uint4 uA1 = *(const uint4*)(T + (size_t)a1 * 64 + h * 8);
        uint4 uA2 = *(const uint4*)(T + (size_t)a2 * 64 + h * 8);
        uint4 uA3 = *(const uint4*)(T + (size_t)a3 * 64 + h * 8);
        uint4 uB0 = *(const uint4*)(T + (size_t)b0 * 64 + h * 8);
        uint4 uB1 = *(const uint4*)(T + (size_t)b1 * 64 + h * 8);
        uint4 uB2 = *(const uint4*)(T + (size_t)b2 * 64 + h * 8);
        uint4 uB3 = *(const uint4*)(T + (size_t)b3 * 64 + h * 8);
        bool tA = (mA > 16), tB = (mB > 16);
        if (tA) {
            int a4 = __shfl(e0, hb + 16 + q), a5 = __shfl(e0, hb + 20 + q);
            int a6 = __shfl(e0, hb + 24 + q), a7 = __shfl(e0, hb + 28 + q);
            uint4 u4 = *(const uint4*)(T + (size_t)a4 * 64 + h * 8);
            uint4 u5 = *(const uint4*)(T + (size_t)a5 * 64 + h * 8);
            uint4 u6 = *(const uint4*)(T + (size_t)a6 * 64 + h * 8);
            uint4 u7 = *(const uint4*)(T + (size_t)a7 * 64 + h * 8);
            addu4(accA, u4); addu4(accA, u5); addu4(accA, u6); addu4(accA, u7);
        }
        if (tB) {
            int b4 = __shfl(e1, hb + 16 + q), b5 = __shfl(e1, hb + 20 + q);
            int b6 = __shfl(e1, hb + 24 + q), b7 = __shfl(e1, hb + 28 + q);
            uint4 u4 = *(const uint4*)(T + (size_t)b4 * 64 + h * 8);
            uint4 u5 = *(const uint4*)(T + (size_t)b5 * 64 + h * 8);
            uint4 u6 = *(const uint4*)(T + (size_t)b6 * 64 + h * 8);
            uint4 u7 = *(const uint4*)(T + (size_t)b7 * 64 + h * 8);
            addu4(accB, u4); addu4(accB, u5); addu4(accB, u6); addu4(accB, u7);
        }
        addu4(accA, uA0); addu4(accA, uA1); addu4(accA, uA2); addu4(accA, uA3);
        addu4(accB, uB0); addu4(accB, uB1); addu4(accB, uB2); addu4(accB, uB3);
    } else {
        agg_loop(T, csr, sA, eA, hb, sub, q, h, accA);
        agg_loop(T, csr, eA, eB, hb, sub, q, h, accB);
    }
    addu4(accA, uSA);
    addu4(accB, uSB);
}

// ---------------- fused agg pass 1 + mid GEMMs ----------------
__global__ __launch_bounds__(256) void k_aggmid(const unsigned short* __restrict__ T,    // Ab (dinv-folded)
                                                const int* __restrict__ csr,
                                                const int* __restrict__ roffE,
                                                const float* __restrict__ bias,          // conv0_b
                                                const unsigned short* __restrict__ WbG,  // conv1 2ks x 4nt
                                                const unsigned short* __restrict__ WbH,  // head0 2ks x 3nt
                                                const float* __restrict__ dinv,
                                                unsigned short* __restrict__ Ab2,        // layer-1 T (dinv-folded)
                                                float* __restrict__ O, int n, int stride) {
    __shared__ unsigned short aLDS[8 * 144];   // 2.3 KB
    int t = threadIdx.x;
    int lane = t & 63, w = t >> 6;
    int half = lane >> 5, sub = lane & 31;
    int q = sub >> 3, h = sub & 7;
    int hb = half << 5;
    int lv = w * 4 + half * 2;
    int v0 = blockIdx.x * 16 + lv;
    bool act = (v0 < n);
    float accA[8] = {0.f, 0.f, 0.f, 0.f, 0.f, 0.f, 0.f, 0.f};
    float accB[8] = {0.f, 0.f, 0.f, 0.f, 0.f, 0.f, 0.f, 0.f};
    float dvA = 0.f, dvB = 0.f;
    if (act) gather2(T, csr, roffE, v0, n, stride, hb, sub, q, h, accA, accB, dvA, dvB);
#pragma unroll
    for (int i = 0; i < 8; i++) {
        accA[i] += __shfl_xor(accA[i], 8);
        accA[i] += __shfl_xor(accA[i], 16);
        accB[i] += __shfl_xor(accB[i], 8);
        accB[i] += __shfl_xor(accB[i], 16);
    }
    if (act && q == 0) {
        float4 b0 = *(const float4*)(bias + h * 8);
        float4 b1 = *(const float4*)(bias + h * 8 + 4);
        float bb[8] = {b0.x, b0.y, b0.z, b0.w, b1.x, b1.y, b1.z, b1.w};
        union { unsigned short hh[8]; uint4 u; } pA, pB;
#pragma unroll
        for (int i = 0; i < 8; i++) {
            float rA = dvA * accA[i] + bb[i];
            rA = (rA > 0.f) ? rA : (__expf(rA) - 1.f);
            pA.hh[i] = f2bf(rA);
            float rB = dvB * accB[i] + bb[i];
            rB = (rB > 0.f) ? rB : (__expf(rB) - 1.f);
            pB.hh[i] = f2bf(rB);
        }
        *(uint4*)(aLDS + h * 144 + lv * 8) = pA.u;
        if (v0 + 1 < n) *(uint4*)(aLDS + h * 144 + (lv + 1) * 8) = pB.u;
    }
    __syncthreads();
    // ---- MFMA phase ----
    int quad = lane >> 4, m = lane & 15;
    short8 afr[2];
#pragma unroll
    for (int ks = 0; ks < 2; ks++)
        afr[ks] = *(const short8*)(aLDS + (ks * 4 + quad) * 144 + m * 8);
    int r0 = blockIdx.x * 16;
    if (w < 2) {
        int nt0 = w * 2;
        float4v a0 = {}, a1 = {};
#pragma unroll
        for (int ks = 0; ks < 2; ks++) {
            short8 bf0 = *(const short8*)(WbG + ((size_t)(ks * 4 + nt0) * 64 + lane) * 8);
            short8 bf1 = *(const short8*)(WbG + ((size_t)(ks * 4 + nt0 + 1) * 64 + lane) * 8);
            a0 = __builtin_amdgcn_mfma_f32_16x16x32_bf16(afr[ks], bf0, a0, 0, 0, 0);
            a1 = __builtin_amdgcn_mfma_f32_16x16x32_bf16(afr[ks], bf1, a1, 0, 0, 0);
        }
#pragma unroll
        for (int reg = 0; reg < 4; reg++) {
            int gr = r0 + quad * 4 + reg;
            if (gr < n) {
                float dv = dinv[gr];
                Ab2[(size_t)gr * 64 + nt0 * 16 + m]       = f2bf(dv * a0[reg]);
                Ab2[(size_t)gr * 64 + (nt0 + 1) * 16 + m] = f2bf(dv * a1[reg]);
            }
        }
    } else {
        int nt0 = (w - 2) * 2;
        int ntc = (w == 2) ? 2 : 1;
        float4v a0 = {}, a1 = {};
#pragma unroll
        for (int ks = 0; ks < 2; ks++) {
            short8 bf0 = *(const short8*)(WbH + ((size_t)(ks * 3 + nt0) * 64 + lane) * 8);
            a0 = __builtin_amdgcn_mfma_f32_16x16x32_bf16(afr[ks], bf0, a0, 0, 0, 0);
        }
        if (ntc == 2) {
#pragma unroll
            for (int ks = 0; ks < 2; ks++) {
                short8 bf1 = *(const short8*)(WbH + ((size_t)(ks * 3 + nt0 + 1) * 64 + lane) * 8);
                a1 = __builtin_amdgcn_mfma_f32_16x16x32_bf16(afr[ks], bf1, a1, 0, 0, 0);
            }
        }
        int col0 = nt0 * 16 + m;
        if (col0 < 40) {
#pragma unroll
            for (int reg = 0; reg < 4; reg++) {
                int gr = r0 + quad * 4 + reg;
                if (gr < n) O[(size_t)gr * 40 + col0] = a0[reg];
            }
        }
        if (ntc == 2) {
            int col1 = (nt0 + 1) * 16 + m;
            if (col1 < 40) {
#pragma unroll
                for (int reg = 0; reg < 4; reg++) {
                    int gr = r0 + quad * 4 + reg;
                    if (gr < n) O[(size_t)gr * 40 + col1] = a1[reg];
                }
            }
        }
    }
}

// ---------------- fused agg pass 2 + final head: O += H1 @ Wf1 + bfv ----------------
__global__ __launch_bounds__(256) void k_agghead(const unsigned short* __restrict__ T,   // Ab2
                                                 const int* __restrict__ csr,
                                                 const int* __restrict__ roffE,
                                                 const float* __restrict__ bias,         // conv1_b
                                                 const unsigned short* __restrict__ Wfb, // head1 2ks x 3nt
                                                 const float* __restrict__ bfv,
                                                 float* __restrict__ O, int n, int stride) {
    __shared__ unsigned short aLDS[8 * 144];
    int t = threadIdx.x;
    int lane = t & 63, w = t >> 6;
    int half = lane >> 5, sub = lane & 31;
    int q = sub >> 3, h = sub & 7;
    int hb = half << 5;
    int lv = w * 4 + half * 2;
    int v0 = blockIdx.x * 16 + lv;
    bool act = (v0 < n);
    float accA[8] = {0.f, 0.f, 0.f, 0.f, 0.f, 0.f, 0.f, 0.f};
    float accB[8] = {0.f, 0.f, 0.f, 0.f, 0.f, 0.f, 0.f, 0.f};
    float dvA = 0.f, dvB = 0.f;
    if (act) gather2(T, csr, roffE, v0, n, stride, hb, sub, q, h, accA, accB, dvA, dvB);
#pragma unroll
    for (int i = 0; i < 8; i++) {
        accA[i] += __shfl_xor(accA[i], 8);
        accA[i] += __shfl_xor(accA[i], 16);
        accB[i] += __shfl_xor(accB[i], 8);
        accB[i] += __shfl_xor(accB[i], 16);
    }
    if (act && q == 0) {
        float4 b0 = *(const float4*)(bias + h * 8);
        float4 b1 = *(const float4*)(bias + h * 8 + 4);
        float bb[8] = {b0.x, b0.y, b0.z, b0.w, b1.x, b1.y, b1.z, b1.w};
        union { unsigned short hh[8]; uint4 u; } pA, pB;
#pragma unroll
        for (int i = 0; i < 8; i++) {
            float rA = dvA * accA[i] + bb[i];
            rA = (rA > 0.f) ? rA : (__expf(rA) - 1.f);
            pA.hh[i] = f2bf(rA);
            float rB = dvB * accB[i] + bb[i];
            rB = (rB > 0.f) ? rB : (__expf(rB) - 1.f);
            pB.hh[i] = f2bf(rB);
        }
        *(uint4*)(aLDS + h * 144 + lv * 8) = pA.u;
        if (v0 + 1 < n) *(uint4*)(aLDS + h * 144 + (lv + 1) * 8) = pB.u;
    }
    __syncthreads();
    int quad = lane >> 4, m = lane & 15;
    short8 afr[2];
#pragma unroll
    for (int ks = 0; ks < 2; ks++)
        afr[ks] = *(const short8*)(aLDS + (ks * 4 + quad) * 144 + m * 8);
    int r0 = blockIdx.x * 16;
    if (w < 3) {
        float4v a0 = {};
#pragma unroll
        for (int ks = 0; ks < 2; ks++) {
            short8 bf0 = *(const short8*)(Wfb + ((size_t)(ks * 3 + w) * 64 + lane) * 8);
            a0 = __builtin_amdgcn_mfma_f32_16x16x32_bf16(afr[ks], bf0, a0, 0, 0, 0);
        }
        int col = w * 16 + m;
        if (col < 40) {
            float bb = bfv[col];
#pragma unroll
            for (int reg = 0; reg < 4; reg++) {
                int gr = r0 + quad * 4 + reg;
                if (gr < n) {
                    size_t p = (size_t)gr * 40 + col;
                    O[p] = O[p] + a0[reg] + bb;
                }
            }
        }
    }
}

// ---------------- launch ----------------

extern "C" void kernel_launch(void* const* d_in, const int* in_sizes, int n_in,
                              void* d_out, int out_size, void* d_ws, size_t ws_size,
                              hipStream_t stream) {
    const float* x       = (const float*)d_in[0];
    const int*   eidx    = (const int*)d_in[1];
    const float* conv0_w = (const float*)d_in[2];
    const float* conv0_b = (const float*)d_in[3];
    const float* lin0_w  = (const float*)d_in[4];
    const float* lin0_b  = (const float*)d_in[5];
    const float* conv1_w = (const float*)d_in[6];
    const float* conv1_b = (const float*)d_in[7];
    const float* lin1_w  = (const float*)d_in[8];
    const float* lin1_b  = (const float*)d_in[9];
    const float* out_w   = (const float*)d_in[10];
    const float* out_b   = (const float*)d_in[11];

    int n = in_sizes[0] / 128;
    int E = in_sizes[1] / 2;
    const int* src = eidx;
    const int* dst = eidx + E;
    int NBUK = (n + 255) >> 8;               // buckets of 256 nodes
    int gC = (E + CHUNK - 1) / CHUNK;
    // strided bucket capacity: 1.5x mean + 1K slack, rounded to 256
    int STRIDE = ((E / NBUK) * 3 / 2 + 1024 + 255) & ~255;

    char* wsb = (char*)d_ws;
    auto al = [](size_t v) { return (v + 4095) & ~(size_t)4095; };
    size_t o = 0;
    int*            gcnt  = (int*)(wsb + o);            o = al(o + 1024 * 4);
    float*          dinv  = (float*)(wsb + o);          o = al(o + (size_t)n * 4);
    int*            roff  = (int*)(wsb + o);            o = al(o + (size_t)n * 4);
    unsigned int*   part  = (unsigned int*)(wsb + o);   o = al(o + (size_t)NBUK * STRIDE * 4);
    int*            csr   = (int*)(wsb + o);            o = al(o + (size_t)NBUK * STRIDE * 4);
    float*          bfv   = (float*)(wsb + o);          o = al(o + 40 * 4);
    unsigned short* Wb0   = (unsigned short*)(wsb + o); o = al(o + 8192 * 2);
    unsigned short* Wb1   = (unsigned short*)(wsb + o); o = al(o + 4096 * 2);
    unsigned short* Wfb0  = (unsigned short*)(wsb + o); o = al(o + 3072 * 2);
    unsigned short* Wfb1  = (unsigned short*)(wsb + o); o = al(o + 3072 * 2);
    unsigned short* Ab    = (unsigned short*)(wsb + o); o = al(o + (size_t)(n + 1) * 64 * 2);  // +1 sentinel
    unsigned short* Ab2   = (unsigned short*)(wsb + o); o = al(o + (size_t)(n + 1) * 64 * 2);  // +1 sentinel
    float* O = (float*)d_out;

    int gT = (n + 63) / 64;      // layer-0 MFMA gemm: 64 rows/block
    int gV2 = (n + 15) / 16;     // fused agg kernels: 16 nodes/block

    // CSR build: 2 kernels (strided buckets, atomic range reservation)
    hipMemsetAsync(gcnt, 0, 1024 * 4, stream);
    k_scat<<<gC, 256, 0, stream>>>(src, dst, gcnt, part, E, STRIDE);
    k_fill2<<<NBUK, 256, 0, stream>>>(part, gcnt, dinv, roff, csr, n, STRIDE);
    k_prep<<<10, 256, 0, stream>>>(conv0_w, conv1_w, lin0_w, lin0_b, lin1_w, lin1_b,
                                   out_w, out_b, Wb0, Wb1, Wfb0, Wfb1, bfv, Ab, Ab2, n);

    // layer 0 transform
    k_gemm_128<<<gT, 256, 0, stream>>>(x, Wb0, dinv, Ab, n);
    // fused: agg pass1 + (Ab2 = dinv*(H0@conv1_w), O = H0@Wf0)
    k_aggmid<<<gV2, 256, 0, stream>>>(Ab, csr, roff, conv0_b, Wb1, Wfb0, dinv, Ab2, O, n, STRIDE);
    // fused: agg pass2 + (O += H1@Wf1 + bfv)
    k_agghead<<<gV2, 256, 0, stream>>>(Ab2, csr, roff, conv1_b, Wfb1, bfv, O, n, STRIDE);
}

// Round 15
// 254.311 us; speedup vs baseline: 1.1882x; 1.0078x over previous
//
#include <hip/hip_runtime.h>

#define DEVFN __device__ __forceinline__

typedef __attribute__((ext_vector_type(8))) short short8;
typedef __attribute__((ext_vector_type(4))) float float4v;
typedef __attribute__((ext_vector_type(2))) float f32x2;

DEVFN float bf2f(unsigned short u) {
    union { unsigned int i; float f; } c;
    c.i = ((unsigned int)u) << 16;
    return c.f;
}

DEVFN unsigned short f2bf(float f) {
    union { float f; unsigned int i; } c;
    c.f = f;
    unsigned int u = c.i;
    return (unsigned short)((u + 0x7FFFu + ((u >> 16) & 1u)) >> 16);  // RNE
}

// accumulate 8 bf16 (uint4) into 4 packed f32x2 accumulators (same adds, same order;
// packed layout lets the compiler emit v_pk_add_f32)
DEVFN void addu4(f32x2* acc, uint4 u) {
    unsigned int w[4] = {u.x, u.y, u.z, u.w};
#pragma unroll
    for (int k = 0; k < 4; k++) {
        union { unsigned int i; float f; } lo, hi;
        lo.i = w[k] << 16;
        hi.i = w[k] & 0xFFFF0000u;
        f32x2 v;
        v.x = lo.f;
        v.y = hi.f;
        acc[k] += v;
    }
}

#define CHUNK 4096

// ---------------- single-pass bucketed scatter (strided buckets, atomic range reserve) ----
__global__ __launch_bounds__(256) void k_scat(const int* __restrict__ src,
                                              const int* __restrict__ dst,
                                              int* __restrict__ gcnt,
                                              unsigned int* __restrict__ part,
                                              int E, int STRIDE) {
    __shared__ int lh[1024];
    __shared__ int lb[1024];
    int t = threadIdx.x;
    for (int b = t; b < 1024; b += 256) lh[b] = 0;
    __syncthreads();
    int i0 = blockIdx.x * CHUNK;
    int d[16];
#pragma unroll
    for (int k = 0; k < 16; k++) {
        int idx = i0 + k * 256 + t;
        d[k] = (idx < E) ? dst[idx] : -1;
        if (d[k] >= 0) atomicAdd(&lh[d[k] >> 8], 1);
    }
    __syncthreads();
    for (int b = t; b < 1024; b += 256) {
        int c = lh[b];
        if (c > 0) lb[b] = b * STRIDE + atomicAdd(&gcnt[b], c);
        lh[b] = 0;  // reuse as cursor
    }
    __syncthreads();
#pragma unroll
    for (int k = 0; k < 16; k++) {
        if (d[k] >= 0) {
            int idx = i0 + k * 256 + t;
            int s = src[idx];
            int b = d[k] >> 8;
            int r = atomicAdd(&lh[b], 1);
            part[lb[b] + r] = (unsigned int)s | ((unsigned int)(d[k] & 255) << 24);
        }
    }
}

// ---------------- per-bucket CSR fill; bucket cached in LDS (one global read of part) -----
__global__ __launch_bounds__(256) void k_fill2(const unsigned int* __restrict__ part,
                                               const int* __restrict__ gcnt,
                                               float* __restrict__ dinv,
                                               int* __restrict__ roff,   // END offsets
                                               int* __restrict__ csr, int n, int STRIDE) {
    __shared__ unsigned int ent[8192];   // 32 KB
    __shared__ int lcnt[256];
    __shared__ int lsc[256];
    __shared__ int lcur[256];
    int b = blockIdx.x, t = threadIdx.x;
    int cnt = gcnt[b];
    int s0 = b * STRIDE;
    bool fits = (cnt <= 8192);
    lcnt[t] = 0;
    __syncthreads();
    if (fits) {
        for (int i = t; i < cnt; i += 256) {
            unsigned int p = part[s0 + i];
            ent[i] = p;
            atomicAdd(&lcnt[p >> 24], 1);
        }
    } else {
        for (int i = t; i < cnt; i += 256) atomicAdd(&lcnt[part[s0 + i] >> 24], 1);
    }
    __syncthreads();
    int v = lcnt[t];
    lsc[t] = v;
    __syncthreads();
    for (int o = 1; o < 256; o <<= 1) {
        int x = (t >= o) ? lsc[t - o] : 0;
        __syncthreads();
        lsc[t] += x;
        __syncthreads();
    }
    int excl = lsc[t] - v;
    int node = (b << 8) + t;
    if (node < n) {
        dinv[node] = rsqrtf((float)(v + 1));  // +1 self-loop
        roff[node] = s0 + excl + v;           // END offset (bucket-strided space)
    }
    lcur[t] = s0 + excl;
    __syncthreads();
    if (fits) {
        for (int i = t; i < cnt; i += 256) {
            unsigned int p = ent[i];
            int pos = atomicAdd(&lcur[p >> 24], 1);
            csr[pos] = (int)(p & 0xFFFFFFu);
        }
    } else {
        for (int i = t; i < cnt; i += 256) {
            unsigned int p = part[s0 + i];
            int pos = atomicAdd(&lcur[p >> 24], 1);
            csr[pos] = (int)(p & 0xFFFFFFu);
        }
    }
}

// ---------------- fused prep (unchanged math) + zero sentinels Ab[n], Ab2[n] ----------------
__global__ __launch_bounds__(256) void k_prep(const float* __restrict__ W0,
                                              const float* __restrict__ W1,
                                              const float* __restrict__ lin0_w, const float* __restrict__ lin0_b,
                                              const float* __restrict__ lin1_w, const float* __restrict__ lin1_b,
                                              const float* __restrict__ out_w, const float* __restrict__ out_b,
                                              unsigned short* __restrict__ Wb0,
                                              unsigned short* __restrict__ Wb1,
                                              unsigned short* __restrict__ Wfb0,
                                              unsigned short* __restrict__ Wfb1,
                                              float* __restrict__ bfv,
                                              unsigned short* __restrict__ Ab,
                                              unsigned short* __restrict__ Ab2, int n) {
    int tid = blockIdx.x * 256 + threadIdx.x;
    if (tid < 1024) {
        int ks = tid >> 8, rem = tid & 255;
        int nt = rem >> 6, lane = rem & 63;
        int quad = lane >> 4, c = lane & 15;
        union { unsigned short h[8]; uint4 u; } p;
#pragma unroll
        for (int j = 0; j < 8; j++)
            p.h[j] = f2bf(W0[(ks * 32 + quad * 8 + j) * 64 + nt * 16 + c]);
        *(uint4*)(Wb0 + (size_t)tid * 8) = p.u;
    } else if (tid < 1536) {
        int t2 = tid - 1024;
        int ks = t2 >> 8, rem = t2 & 255;
        int nt = rem >> 6, lane = rem & 63;
        int quad = lane >> 4, c = lane & 15;
        union { unsigned short h[8]; uint4 u; } p;
#pragma unroll
        for (int j = 0; j < 8; j++)
            p.h[j] = f2bf(W1[(ks * 32 + quad * 8 + j) * 64 + nt * 16 + c]);
        *(uint4*)(Wb1 + (size_t)t2 * 8) = p.u;
    } else if (tid < 1920) {
        int t2 = tid - 1536;          // 0..383
        int ks = t2 / 192;
        int rem = t2 % 192;
        int nt = rem >> 6, lane = rem & 63;
        int quad = lane >> 4, c = lane & 15;
        int col = nt * 16 + c;
        union { unsigned short h[8]; uint4 u; } p;
#pragma unroll
        for (int j = 0; j < 8; j++) {
            unsigned short r = 0;
            if (col < 40) {
                int i = ks * 32 + quad * 8 + j;
                float a = 0.f;
                for (int k = 0; k < 64; k++) a += lin0_w[i * 64 + k] * out_w[k * 40 + col];
                r = f2bf(a);
            }
            p.h[j] = r;
        }
        *(uint4*)(Wfb0 + ((size_t)(ks * 3 + nt) * 64 + lane) * 8) = p.u;
    } else if (tid < 2304) {
        int t2 = tid - 1920;
        int ks = t2 / 192;
        int rem = t2 % 192;
        int nt = rem >> 6, lane = rem & 63;
        int quad = lane >> 4, c = lane & 15;
        int col = nt * 16 + c;
        union { unsigned short h[8]; uint4 u; } p;
#pragma unroll
        for (int j = 0; j < 8; j++) {
            unsigned short r = 0;
            if (col < 40) {
                int i = ks * 32 + quad * 8 + j;
                float a = 0.f;
                for (int k = 0; k < 64; k++) a += lin1_w[i * 64 + k] * out_w[(64 + k) * 40 + col];
                r = f2bf(a);
            }
            p.h[j] = r;
        }
        *(uint4*)(Wfb1 + ((size_t)(ks * 3 + nt) * 64 + lane) * 8) = p.u;
    } else if (tid < 2344) {
        int j = tid - 2304;
        float a = out_b[j];
        for (int k = 0; k < 64; k++) {
            a += lin0_b[k] * out_w[k * 40 + j];
            a += lin1_b[k] * out_w[(64 + k) * 40 + j];
        }
        bfv[j] = a;
    } else if (tid < 2352) {
        uint4 z = {0u, 0u, 0u, 0u};
        *(uint4*)(Ab + (size_t)n * 64 + (tid - 2344) * 8) = z;
    } else if (tid < 2360) {
        uint4 z = {0u, 0u, 0u, 0u};
        *(uint4*)(Ab2 + (size_t)n * 64 + (tid - 2352) * 8) = z;
    }
}

// ---------------- MFMA transform GEMM (layer 0, fp32 input K=128) ----------------

__global__ __launch_bounds__(256) void k_gemm_128(const float* __restrict__ A,
                                                  const unsigned short* __restrict__ Wb,
                                                  const float* __restrict__ dinv,
                                                  unsigned short* __restrict__ Cb, int n) {
    __shared__ unsigned short aLDS[64 * 144];  // 18 KB
    int t = threadIdx.x;
    int r0 = blockIdx.x * 64;
    for (int idx = t; idx < 2048; idx += 256) {   // 64 rows x 32 float4
        int r = idx >> 5;
        int k = (idx & 31) << 2;
        int gr = r0 + r; if (gr >= n) gr = n - 1;
        float4 u = *(const float4*)(A + (size_t)gr * 128 + k);
        int tile = r >> 4, m = r & 15;
        int ks = k >> 5, quad = (k >> 3) & 3, j0 = k & 7;
        int g = (tile * 4 + ks) * 4 + quad;
        union { unsigned short h[4]; uint2 u2; } pk;
        pk.h[0] = f2bf(u.x); pk.h[1] = f2bf(u.y); pk.h[2] = f2bf(u.z); pk.h[3] = f2bf(u.w);
        *(uint2*)(aLDS + g * 144 + m * 8 + j0) = pk.u2;
    }
    int lane = t & 63;
    int w = t >> 6;
    short8 bfr[4][4];
#pragma unroll
    for (int ks = 0; ks < 4; ks++)
#pragma unroll
        for (int nt = 0; nt < 4; nt++)
            bfr[ks][nt] = *(const short8*)(Wb + ((size_t)(ks * 4 + nt) * 64 + lane) * 8);
    __syncthreads();
    int quad = lane >> 4, m = lane & 15;
    short8 afr[4];
#pragma unroll
    for (int ks = 0; ks < 4; ks++)
        afr[ks] = *(const short8*)(aLDS + ((w * 4 + ks) * 4 + quad) * 144 + m * 8);
    float4v acc[4] = {};
#pragma unroll
    for (int nt = 0; nt < 4; nt++)
#pragma unroll
        for (int ks = 0; ks < 4; ks++)
            acc[nt] = __builtin_amdgcn_mfma_f32_16x16x32_bf16(afr[ks], bfr[ks][nt], acc[nt], 0, 0, 0);
    float dv[4];
#pragma unroll
    for (int reg = 0; reg < 4; reg++) {
        int gr = r0 + w * 16 + quad * 4 + reg;
        dv[reg] = (gr < n) ? dinv[gr] : 0.f;
    }
#pragma unroll
    for (int nt = 0; nt < 4; nt++)
#pragma unroll
        for (int reg = 0; reg < 4; reg++) {
            int gr = r0 + w * 16 + quad * 4 + reg;
            if (gr < n) Cb[(size_t)gr * 64 + nt * 16 + m] = f2bf(dv[reg] * acc[nt][reg]);
        }
}

// ---------------- generic per-node aggregation loop (rare deg>32 path) ----------------
DEVFN void agg_loop(const unsigned short* __restrict__ T, const int* __restrict__ csr,
                    int start, int end, int hb, int sub, int q, int h, f32x2* acc) {
    for (int base = start; base < end; base += 32) {
        int m = end - base; if (m > 32) m = 32;
        int e = (sub < m) ? csr[base + sub] : 0;
        int j = 0;
        for (; j + 16 <= m; j += 16) {
            int s0 = __shfl(e, hb + j + q);
            int s1 = __shfl(e, hb + j + 4 + q);
            int s2 = __shfl(e, hb + j + 8 + q);
            int s3 = __shfl(e, hb + j + 12 + q);
            uint4 u0 = *(const uint4*)(T + (size_t)s0 * 64 + h * 8);
            uint4 u1 = *(const uint4*)(T + (size_t)s1 * 64 + h * 8);
            uint4 u2 = *(const uint4*)(T + (size_t)s2 * 64 + h * 8);
            uint4 u3 = *(const uint4*)(T + (size_t)s3 * 64 + h * 8);
            addu4(acc, u0); addu4(acc, u1); addu4(acc, u2); addu4(acc, u3);
        }
        if (j + 8 <= m) {
            int s0 = __shfl(e, hb + j + q);
            int s1 = __shfl(e, hb + j + 4 + q);
            uint4 u0 = *(const uint4*)(T + (size_t)s0 * 64 + h * 8);
            uint4 u1 = *(const uint4*)(T + (size_t)s1 * 64 + h * 8);
            addu4(acc, u0); addu4(acc, u1);
            j += 8;
        }
        if (j + 4 <= m) {
            int s = __shfl(e, hb + j + q);
            uint4 u = *(const uint4*)(T + (size_t)s * 64 + h * 8);
            addu4(acc, u);
            j += 4;
        }
        if (j < m) {
            int jj = j + q;
            int s = __shfl(e, hb + (jj & 31));
            if (jj < m) {
                uint4 u = *(const uint4*)(T + (size_t)s * 64 + h * 8);
                addu4(acc, u);
            }
        }
    }
}

// gather for the node pair (v0, v0+1); bucket-strided CSR space.
DEVFN void gather2(const unsigned short* __restrict__ T, const int* __restrict__ csr,
                   const int* __restrict__ roffE, int v0, int n, int stride,
                   int hb, int sub, int q, int h,
                   f32x2* accA, f32x2* accB, float& dvA, float& dvB) {
    int v1 = v0 + 1;
    bool has1 = (v1 < n);
    int sA = ((v0 & 255) == 0) ? (v0 >> 8) * stride : roffE[v0 - 1];
    int eA = roffE[v0];
    int eB = has1 ? roffE[v1] : eA;
    int mA = eA - sA;
    int mB = eB - eA;
    dvA = rsqrtf((float)(mA + 1));
    dvB = rsqrtf((float)(mB + 1));
    uint4 uSA = {0u, 0u, 0u, 0u}, uSB = {0u, 0u, 0u, 0u};
    if (q == 0) {
        uSA = *(const uint4*)(T + (size_t)v0 * 64 + h * 8);
        if (has1) uSB = *(const uint4*)(T + (size_t)v1 * 64 + h * 8);
    }
    if (mA <= 32 && mB <= 32) {
        int e0 = (sub < mA) ? csr[sA + sub] : n;   // sentinel -> zero row
        int e1 = (sub < mB) ? csr[eA + sub] : n;
        int a0 = __shfl(e0, hb + q),      a1 = __shfl(e0, hb + 4 + q);
        int a2 = __shfl(e0, hb + 8 + q),  a3 = __shfl(e0, hb + 12 + q);
        int b0 = __shfl(e1, hb + q),      b1 = __shfl(e1, hb + 4 + q);
        int b2 = __shfl(e1, hb + 8 + q),  b3 = __shfl(e1, hb + 12 + q);
        uint4 uA0 = *(const uint4*)(T + (size_t)a0 * 64 + h * 8);
        uint4 uA1 = *(const uint4*)(T + (size_t)a1 * 64 + h * 8);
        uint4 uA2 = *(const uint4*)(T + (size_t)a2 * 64 + h * 8);
        uint4 uA3 = *(const uint4*)(T + (size_t)a3 * 64 + h * 8);
        uint4 uB0 = *(const uint4*)(T + (size_t)b0 * 64 + h * 8);
        uint4 uB1 = *(const uint4*)(T + (size_t)b1 * 64 + h * 8);
        uint4 uB2 = *(const uint4*)(T + (size_t)b2 * 64 + h * 8);
        uint4 uB3 = *(const uint4*)(T + (size_t)b3 * 64 + h * 8);
        bool tA = (mA > 16), tB = (mB > 16);
        if (tA) {
            int a4 = __shfl(e0, hb + 16 + q), a5 = __shfl(e0, hb + 20 + q);
            int a6 = __shfl(e0, hb + 24 + q), a7 = __shfl(e0, hb + 28 + q);
            uint4 u4 = *(const uint4*)(T + (size_t)a4 * 64 + h * 8);
            uint4 u5 = *(const uint4*)(T + (size_t)a5 * 64 + h * 8);
            uint4 u6 = *(const uint4*)(T + (size_t)a6 * 64 + h * 8);
            uint4 u7 = *(const uint4*)(T + (size_t)a7 * 64 + h * 8);
            addu4(accA, u4); addu4(accA, u5); addu4(accA, u6); addu4(accA, u7);
        }
        if (tB) {
            int b4 = __shfl(e1, hb + 16 + q), b5 = __shfl(e1, hb + 20 + q);
            int b6 = __shfl(e1, hb + 24 + q), b7 = __shfl(e1, hb + 28 + q);
            uint4 u4 = *(const uint4*)(T + (size_t)b4 * 64 + h * 8);
            uint4 u5 = *(const uint4*)(T + (size_t)b5 * 64 + h * 8);
            uint4 u6 = *(const uint4*)(T + (size_t)b6 * 64 + h * 8);
            uint4 u7 = *(const uint4*)(T + (size_t)b7 * 64 + h * 8);
            addu4(accB, u4); addu4(accB, u5); addu4(accB, u6); addu4(accB, u7);
        }
        addu4(accA, uA0); addu4(accA, uA1); addu4(accA, uA2); addu4(accA, uA3);
        addu4(accB, uB0); addu4(accB, uB1); addu4(accB, uB2); addu4(accB, uB3);
    } else {
        agg_loop(T, csr, sA, eA, hb, sub, q, h, accA);
        agg_loop(T, csr, eA, eB, hb, sub, q, h, accB);
    }
    addu4(accA, uSA);
    addu4(accB, uSB);
}

// component-wise q-reduce preserving per-accumulator add order
DEVFN void qreduce(f32x2* acc) {
#pragma unroll
    for (int k = 0; k < 4; k++) {
        acc[k].x += __shfl_xor(acc[k].x, 8);
        acc[k].x += __shfl_xor(acc[k].x, 16);
        acc[k].y += __shfl_xor(acc[k].y, 8);
        acc[k].y += __shfl_xor(acc[k].y, 16);
    }
}

// ---------------- fused agg pass 1 + conv1 GEMM; stores H0 (bf16) for the head ----------
// Waves 0-1: conv1 MFMA -> Ab2 (dinv-folded).  Waves 2-3: dump the 16x64 H0 LDS tile to
// global H0b (2 KB/block) — head0 GEMM moves to k_agghead, removing the O fp32 RMW.
__global__ __launch_bounds__(256) void k_aggmid(const unsigned short* __restrict__ T,    // Ab (dinv-folded)
                                                const int* __restrict__ csr,
                                                const int* __restrict__ roffE,
                                                const float* __restrict__ bias,          // conv0_b
                                                const unsigned short* __restrict__ WbG,  // conv1 2ks x 4nt
                                                const float* __restrict__ dinv,
                                                unsigned short* __restrict__ Ab2,        // layer-1 T (dinv-folded)
                                                unsigned short* __restrict__ H0b,        // [n][64] bf16
                                                int n, int stride) {
    __shared__ unsigned short aLDS[8 * 144];   // 2.3 KB
    int t = threadIdx.x;
    int lane = t & 63, w = t >> 6;
    int half = lane >> 5, sub = lane & 31;
    int q = sub >> 3, h = sub & 7;
    int hb = half << 5;
    int lv = w * 4 + half * 2;
    int v0 = blockIdx.x * 16 + lv;
    bool act = (v0 < n);
    f32x2 accA[4] = {};
    f32x2 accB[4] = {};
    float dvA = 0.f, dvB = 0.f;
    if (act) gather2(T, csr, roffE, v0, n, stride, hb, sub, q, h, accA, accB, dvA, dvB);
    qreduce(accA);
    qreduce(accB);
    if (act && q == 0) {
        float4 b0 = *(const float4*)(bias + h * 8);
        float4 b1 = *(const float4*)(bias + h * 8 + 4);
        float bb[8] = {b0.x, b0.y, b0.z, b0.w, b1.x, b1.y, b1.z, b1.w};
        float aA[8] = {accA[0].x, accA[0].y, accA[1].x, accA[1].y, accA[2].x, accA[2].y, accA[3].x, accA[3].y};
        float aB[8] = {accB[0].x, accB[0].y, accB[1].x, accB[1].y, accB[2].x, accB[2].y, accB[3].x, accB[3].y};
        union { unsigned short hh[8]; uint4 u; } pA, pB;
#pragma unroll
        for (int i = 0; i < 8; i++) {
            float rA = dvA * aA[i] + bb[i];
            rA = (rA > 0.f) ? rA : (__expf(rA) - 1.f);
            pA.hh[i] = f2bf(rA);
            float rB = dvB * aB[i] + bb[i];
            rB = (rB > 0.f) ? rB : (__expf(rB) - 1.f);
            pB.hh[i] = f2bf(rB);
        }
        *(uint4*)(aLDS + h * 144 + lv * 8) = pA.u;
        if (v0 + 1 < n) *(uint4*)(aLDS + h * 144 + (lv + 1) * 8) = pB.u;
    }
    __syncthreads();
    int quad = lane >> 4, m = lane & 15;
    int r0 = blockIdx.x * 16;
    if (w < 2) {
        short8 afr[2];
#pragma unroll
        for (int ks = 0; ks < 2; ks++)
            afr[ks] = *(const short8*)(aLDS + (ks * 4 + quad) * 144 + m * 8);
        int nt0 = w * 2;
        float4v a0 = {}, a1 = {};
#pragma unroll
        for (int ks = 0; ks < 2; ks++) {
            short8 bf0 = *(const short8*)(WbG + ((size_t)(ks * 4 + nt0) * 64 + lane) * 8);
            short8 bf1 = *(const short8*)(WbG + ((size_t)(ks * 4 + nt0 + 1) * 64 + lane) * 8);
            a0 = __builtin_amdgcn_mfma_f32_16x16x32_bf16(afr[ks], bf0, a0, 0, 0, 0);
            a1 = __builtin_amdgcn_mfma_f32_16x16x32_bf16(afr[ks], bf1, a1, 0, 0, 0);
        }
#pragma unroll
        for (int reg = 0; reg < 4; reg++) {
            int gr = r0 + quad * 4 + reg;
            if (gr < n) {
                float dv = dinv[gr];
                Ab2[(size_t)gr * 64 + nt0 * 16 + m]       = f2bf(dv * a0[reg]);
                Ab2[(size_t)gr * 64 + (nt0 + 1) * 16 + m] = f2bf(dv * a1[reg]);
            }
        }
    } else {
        // dump H0 tile (exact LDS bytes) to global
        int t2 = t - 128;            // 0..127
        int r = t2 >> 3, c = t2 & 7;
        int gr = r0 + r;
        if (gr < n) {
            uint4 u = *(const uint4*)(aLDS + c * 144 + r * 8);
            *(uint4*)(H0b + (size_t)gr * 64 + c * 8) = u;
        }
    }
}

// ---------------- fused agg pass 2 + BOTH head GEMMs: O = H0@Wf0 + H1@Wf1 + bfv ---------
__global__ __launch_bounds__(256) void k_agghead(const unsigned short* __restrict__ T,   // Ab2
                                                 const int* __restrict__ csr,
                                                 const int* __restrict__ roffE,
                                                 const float* __restrict__ bias,         // conv1_b
                                                 const unsigned short* __restrict__ H0b, // [n][64] bf16
                                                 const unsigned short* __restrict__ Wfb0,// head0 2ks x 3nt
                                                 const unsigned short* __restrict__ Wfb1,// head1 2ks x 3nt
                                                 const float* __restrict__ bfv,
                                                 float* __restrict__ O, int n, int stride) {
    __shared__ unsigned short aLDS[8 * 144];    // H1 tile
    __shared__ unsigned short aLDS0[8 * 144];   // H0 tile
    int t = threadIdx.x;
    int lane = t & 63, w = t >> 6;
    int half = lane >> 5, sub = lane & 31;
    int q = sub >> 3, h = sub & 7;
    int hb = half << 5;
    int lv = w * 4 + half * 2;
    int v0 = blockIdx.x * 16 + lv;
    bool act = (v0 < n);
    // stage H0 tile early (t<128): 16 rows x 64 bf16
    if (t < 128) {
        int r = t >> 3, c = t & 7;
        int gr = blockIdx.x * 16 + r; if (gr >= n) gr = n - 1;
        uint4 u = *(const uint4*)(H0b + (size_t)gr * 64 + c * 8);
        *(uint4*)(aLDS0 + c * 144 + r * 8) = u;
    }
    f32x2 accA[4] = {};
    f32x2 accB[4] = {};
    float dvA = 0.f, dvB = 0.f;
    if (act) gather2(T, csr, roffE, v0, n, stride, hb, sub, q, h, accA, accB, dvA, dvB);
    qreduce(accA);
    qreduce(accB);
    if (act && q == 0) {
        float4 b0 = *(const float4*)(bias + h * 8);
        float4 b1 = *(const float4*)(bias + h * 8 + 4);
        float bb[8] = {b0.x, b0.y, b0.z, b0.w, b1.x, b1.y, b1.z, b1.w};
        float aA[8] = {accA[0].x, accA[0].y, accA[1].x, accA[1].y, accA[2].x, accA[2].y, accA[3].x, accA[3].y};
        float aB[8] = {accB[0].x, accB[0].y, accB[1].x, accB[1].y, accB[2].x, accB[2].y, accB[3].x, accB[3].y};
        union { unsigned short hh[8]; uint4 u; } pA, pB;
#pragma unroll
        for (int i = 0; i < 8; i++) {
            float rA = dvA * aA[i] + bb[i];
            rA = (rA > 0.f) ? rA : (__expf(rA) - 1.f);
            pA.hh[i] = f2bf(rA);
            float rB = dvB * aB[i] + bb[i];
            rB = (rB > 0.f) ? rB : (__expf(rB) - 1.f);
            pB.hh[i] = f2bf(rB);
        }
        *(uint4*)(aLDS + h * 144 + lv * 8) = pA.u;
        if (v0 + 1 < n) *(uint4*)(aLDS + h * 144 + (lv + 1) * 8) = pB.u;
    }
    __syncthreads();
    int quad = lane >> 4, m = lane & 15;
    int r0 = blockIdx.x * 16;
    if (w < 3) {
        short8 h0fr[2], h1fr[2];
#pragma unroll
        for (int ks = 0; ks < 2; ks++) {
            h0fr[ks] = *(const short8*)(aLDS0 + (ks * 4 + quad) * 144 + m * 8);
            h1fr[ks] = *(const short8*)(aLDS  + (ks * 4 + quad) * 144 + m * 8);
        }
        float4v a0 = {}, a1 = {};
#pragma unroll
        for (int ks = 0; ks < 2; ks++) {
            short8 bf0 = *(const short8*)(Wfb0 + ((size_t)(ks * 3 + w) * 64 + lane) * 8);
            a0 = __builtin_amdgcn_mfma_f32_16x16x32_bf16(h0fr[ks], bf0, a0, 0, 0, 0);
        }
#pragma unroll
        for (int ks = 0; ks < 2; ks++) {
            short8 bf1 = *(const short8*)(Wfb1 + ((size_t)(ks * 3 + w) * 64 + lane) * 8);
            a1 = __builtin_amdgcn_mfma_f32_16x16x32_bf16(h1fr[ks], bf1, a1, 0, 0, 0);
        }
        int col = w * 16 + m;
        if (col < 40) {
            float bb = bfv[col];
#pragma unroll
            for (int reg = 0; reg < 4; reg++) {
                int gr = r0 + quad * 4 + reg;
                if (gr < n) {
                    O[(size_t)gr * 40 + col] = a0[reg] + a1[reg] + bb;
                }
            }
        }
    }
}

// ---------------- launch ----------------

extern "C" void kernel_launch(void* const* d_in, const int* in_sizes, int n_in,
                              void* d_out, int out_size, void* d_ws, size_t ws_size,
                              hipStream_t stream) {
    const float* x       = (const float*)d_in[0];
    const int*   eidx    = (const int*)d_in[1];
    const float* conv0_w = (const float*)d_in[2];
    const float* conv0_b = (const float*)d_in[3];
    const float* lin0_w  = (const float*)d_in[4];
    const float* lin0_b  = (const float*)d_in[5];
    const float* conv1_w = (const float*)d_in[6];
    const float* conv1_b = (const float*)d_in[7];
    const float* lin1_w  = (const float*)d_in[8];
    const float* lin1_b  = (const float*)d_in[9];
    const float* out_w   = (const float*)d_in[10];
    const float* out_b   = (const float*)d_in[11];

    int n = in_sizes[0] / 128;
    int E = in_sizes[1] / 2;
    const int* src = eidx;
    const int* dst = eidx + E;
    int NBUK = (n + 255) >> 8;               // buckets of 256 nodes
    int gC = (E + CHUNK - 1) / CHUNK;
    // strided bucket capacity: 1.5x mean + 1K slack, rounded to 256
    int STRIDE = ((E / NBUK) * 3 / 2 + 1024 + 255) & ~255;

    char* wsb = (char*)d_ws;
    auto al = [](size_t v) { return (v + 4095) & ~(size_t)4095; };
    size_t o = 0;
    int*            gcnt  = (int*)(wsb + o);            o = al(o + 1024 * 4);
    float*          dinv  = (float*)(wsb + o);          o = al(o + (size_t)n * 4);
    int*            roff  = (int*)(wsb + o);            o = al(o + (size_t)n * 4);
    unsigned int*   part  = (unsigned int*)(wsb + o);   o = al(o + (size_t)NBUK * STRIDE * 4);
    int*            csr   = (int*)(wsb + o);            o = al(o + (size_t)NBUK * STRIDE * 4);
    float*          bfv   = (float*)(wsb + o);          o = al(o + 40 * 4);
    unsigned short* Wb0   = (unsigned short*)(wsb + o); o = al(o + 8192 * 2);
    unsigned short* Wb1   = (unsigned short*)(wsb + o); o = al(o + 4096 * 2);
    unsigned short* Wfb0  = (unsigned short*)(wsb + o); o = al(o + 3072 * 2);
    unsigned short* Wfb1  = (unsigned short*)(wsb + o); o = al(o + 3072 * 2);
    unsigned short* Ab    = (unsigned short*)(wsb + o); o = al(o + (size_t)(n + 1) * 64 * 2);  // +1 sentinel
    unsigned short* Ab2   = (unsigned short*)(wsb + o); o = al(o + (size_t)(n + 1) * 64 * 2);  // +1 sentinel
    unsigned short* H0b   = (unsigned short*)(wsb + o); o = al(o + (size_t)n * 64 * 2);
    float* O = (float*)d_out;

    int gT = (n + 63) / 64;      // layer-0 MFMA gemm: 64 rows/block
    int gV2 = (n + 15) / 16;     // fused agg kernels: 16 nodes/block

    // CSR build: 2 kernels (strided buckets, atomic range reservation)
    hipMemsetAsync(gcnt, 0, 1024 * 4, stream);
    k_scat<<<gC, 256, 0, stream>>>(src, dst, gcnt, part, E, STRIDE);
    k_fill2<<<NBUK, 256, 0, stream>>>(part, gcnt, dinv, roff, csr, n, STRIDE);
    k_prep<<<10, 256, 0, stream>>>(conv0_w, conv1_w, lin0_w, lin0_b, lin1_w, lin1_b,
                                   out_w, out_b, Wb0, Wb1, Wfb0, Wfb1, bfv, Ab, Ab2, n);

    // layer 0 transform
    k_gemm_128<<<gT, 256, 0, stream>>>(x, Wb0, dinv, Ab, n);
    // fused: agg pass1 + (Ab2 = dinv*(H0@conv1_w)); stores H0 bf16
    k_aggmid<<<gV2, 256, 0, stream>>>(Ab, csr, roff, conv0_b, Wb1, dinv, Ab2, H0b, n, STRIDE);
    // fused: agg pass2 + (O = H0@Wf0 + H1@Wf1 + bfv), single O write
    k_agghead<<<gV2, 256, 0, stream>>>(Ab2, csr, roff, conv1_b, H0b, Wfb0, Wfb1, bfv, O, n, STRIDE);
}